// Round 14
// baseline (314.273 us; speedup 1.0000x reference)
//
#include <hip/hip_runtime.h>

// ---------------------------------------------------------------------------
// ROIAwareGCN: 3x GCNConv + mean-pool + MLP.
// R1: atomic pool -> segmented reduction. R2: split-bf16 MFMA GEMM, bf16 t.
// R3: padded CSR. R4: pool+mlp fused. R5/R6: single-block scan.
// R7: bucket atomics REGRESSED. R8: LDS sort CRASHED. R9: col-only NEUTRAL.
// R10: wgt[] eliminated (dinv in GEMM epilogue; pad cols -> zero row n).
// R11: scan split into k_sum/k_out across 13 CUs.
// R12: rows padded to 16 NEUTRAL -- aggs are gather-THROUGHPUT bound; TLP
//      (12.5k waves) already hides latency, deeper per-wave ILP is moot.
// R13: k_csr scatter was the last line-ping-pong kernel (R6: 67MB WRITE).
//      Now XCD-partitioned: block part = blockIdx%8 (round-robin XCD
//      heuristic) writes only dsts with dst>>13 == part -> each col region
//      written from one XCD, lines written back once. 8x redundant dst reads
//      are L3-absorbed. Fused with gemm1 (independent after k_out) so the
//      gemm slot hides under csr. Heuristic affects speed only, not
//      correctness.
// ---------------------------------------------------------------------------

typedef __bf16 bf16x8 __attribute__((ext_vector_type(8)));
typedef float f32x4 __attribute__((ext_vector_type(4)));

__device__ __forceinline__ float bflo(unsigned u) { return __uint_as_float(u << 16); }
__device__ __forceinline__ float bfhi(unsigned u) { return __uint_as_float(u & 0xffff0000u); }

union BF2 {
    __bf16 h[2];
    unsigned u;
};

// ---------------- W pre-pack into MFMA B-fragment layout ----------------
__device__ __forceinline__ void wpack_block(const float* __restrict__ W,
                                            __bf16* __restrict__ hi,
                                            __bf16* __restrict__ lo, int N, int b, int l) {
    int t = b >> 2, c = b & 3;
    int k0 = c * 32 + (l >> 4) * 8;
    int ncol = t * 16 + (l & 15);
    size_t base = ((size_t)b * 64 + l) * 8;
#pragma unroll
    for (int j = 0; j < 8; j++) {
        float v = W[(size_t)(k0 + j) * N + ncol];
        __bf16 h = (__bf16)v;
        hi[base + j] = h;
        lo[base + j] = (__bf16)(v - (float)h);
    }
}

// ---- fused: degree count + graph boundaries + wpack(W1,W2,W3) ----
__global__ void k_pre(const int* __restrict__ dst, int* __restrict__ cnt,
                      const int* __restrict__ batch, int* __restrict__ gstart,
                      const float* __restrict__ W1, __bf16* __restrict__ Wp1h,
                      __bf16* __restrict__ Wp1l,
                      const float* __restrict__ W2, const float* __restrict__ W3,
                      __bf16* __restrict__ Wp2h, __bf16* __restrict__ Wp2l,
                      __bf16* __restrict__ Wp3h, __bf16* __restrict__ Wp3l,
                      int E, int n, int G, int EB) {
    int b = blockIdx.x;
    if (b < EB) {
        int e = b * 256 + threadIdx.x;
        if (e < E) atomicAdd(&cnt[dst[e]], 1);
    } else if (b == EB) {
        int g = threadIdx.x;
        if (g <= G) {
            int lo = 0, hi = n;
            while (lo < hi) {
                int mid = (lo + hi) >> 1;
                if (batch[mid] < g) lo = mid + 1; else hi = mid;
            }
            gstart[g] = lo;  // lower_bound: first i with batch[i] >= g
        }
    } else {
        int b64 = (b - EB - 1) * 4 + (threadIdx.x >> 6);  // 0..79
        int l = threadIdx.x & 63;
        if (b64 < 32) wpack_block(W1, Wp1h, Wp1l, 128, b64, l);
        else if (b64 < 64) wpack_block(W2, Wp2h, Wp2l, 128, b64 - 32, l);
        else if (b64 < 80) wpack_block(W3, Wp3h, Wp3l, 64, b64 - 64, l);
    }
}

#define PAD(c) (((c) + 15) & ~15)

// ---------------- scan stage 1: per-chunk padded sums + dinv ----------------
__global__ __launch_bounds__(1024) void k_sum(const int* __restrict__ cnt,
                                              int* __restrict__ partial,
                                              float* __restrict__ dinv,
                                              unsigned int* __restrict__ tz128,
                                              unsigned int* __restrict__ tz64, int n) {
    __shared__ int ws[16];
    int b = blockIdx.x;
    int tid = threadIdx.x;
    int lane = tid & 63;
    int wid = tid >> 6;
    if (b == 0) {  // zero row n of the two gather targets (64 + 32 uints)
        if (tid < 64) tz128[(size_t)n * 64 + tid] = 0u;
        else if (tid < 96) tz64[(size_t)n * 32 + (tid - 64)] = 0u;
    }
    int i0 = (b << 12) + tid * 4;
    int s = 0;
    if (i0 + 3 < n) {
        int4 v = *(const int4*)(cnt + i0);
        float4 dv;
        dv.x = rsqrtf((float)(v.x + 1));
        dv.y = rsqrtf((float)(v.y + 1));
        dv.z = rsqrtf((float)(v.z + 1));
        dv.w = rsqrtf((float)(v.w + 1));
        *(float4*)(dinv + i0) = dv;
        s = PAD(v.x) + PAD(v.y) + PAD(v.z) + PAD(v.w);
    } else if (i0 < n) {
#pragma unroll
        for (int j = 0; j < 4; j++) {
            if (i0 + j < n) {
                int v = cnt[i0 + j];
                dinv[i0 + j] = rsqrtf((float)(v + 1));
                s += PAD(v);
            }
        }
    }
#pragma unroll
    for (int d = 32; d > 0; d >>= 1) s += __shfl_xor(s, d);
    if (lane == 0) ws[wid] = s;
    __syncthreads();
    if (tid == 0) {
        int t = 0;
#pragma unroll
        for (int k = 0; k < 16; k++) t += ws[k];
        partial[b] = t;
    }
}

// ---------------- scan stage 2: in-block scan + outputs ----------------
__global__ __launch_bounds__(1024) void k_out(const int* __restrict__ cnt,
                                              const int* __restrict__ partial,
                                              int* __restrict__ rowptr,
                                              int* __restrict__ fill2,
                                              int* __restrict__ col,
                                              int n, int nchunks) {
    __shared__ int lsum[16];
    __shared__ int base_s;
    int b = blockIdx.x;
    int tid = threadIdx.x;
    int lane = tid & 63;
    int wid = tid >> 6;
    if (tid == 0) {
        int acc = 0;
        for (int c = 0; c < b; c++) acc += partial[c];
        base_s = acc;
    }
    if (b == 0 && tid == 1) {  // total -> rowptr[n]
        int acc = 0;
        for (int c = 0; c < nchunks; c++) acc += partial[c];
        rowptr[n] = acc;
    }
    int i0 = (b << 12) + tid * 4;
    int v[4], pv[4];
    int s = 0;
    if (i0 < n) {
        if (i0 + 3 < n) {
            int4 vv = *(const int4*)(cnt + i0);
            v[0] = vv.x; v[1] = vv.y; v[2] = vv.z; v[3] = vv.w;
        } else {
#pragma unroll
            for (int j = 0; j < 4; j++) v[j] = (i0 + j < n) ? cnt[i0 + j] : 0;
        }
    } else {
#pragma unroll
        for (int j = 0; j < 4; j++) v[j] = 0;
    }
#pragma unroll
    for (int j = 0; j < 4; j++) {
        pv[j] = PAD(v[j]);
        s += pv[j];
    }
    int sc = s;
#pragma unroll
    for (int d = 1; d < 64; d <<= 1) {
        int o = __shfl_up(sc, d);
        if (lane >= d) sc += o;
    }
    int exc = sc - s;
    if (lane == 63) lsum[wid] = sc;
    __syncthreads();
    if (wid == 0) {
        int val = (lane < 16) ? lsum[lane] : 0;
        int sc2 = val;
#pragma unroll
        for (int d = 1; d < 16; d <<= 1) {
            int o = __shfl_up(sc2, d);
            if (lane >= d) sc2 += o;
        }
        if (lane < 16) lsum[lane] = sc2 - val;
    }
    __syncthreads();
    if (i0 >= n) return;
    int off = base_s + lsum[wid] + exc;
    int o0 = off;
    int o1 = o0 + pv[0];
    int o2 = o1 + pv[1];
    int o3 = o2 + pv[2];
    int o4 = o3 + pv[3];
    if (i0 + 3 < n) {
        int4 ov = {o0, o1, o2, o3};
        *(int4*)(rowptr + i0) = ov;
        *(int4*)(fill2 + i0) = ov;
    } else {
        int oo[4] = {o0, o1, o2, o3};
#pragma unroll
        for (int j = 0; j < 4; j++) {
            if (i0 + j < n) {
                rowptr[i0 + j] = oo[j];
                fill2[i0 + j] = oo[j];
            }
        }
    }
    for (int p = o0 + v[0]; p < o1; p++) col[p] = n;
    if (i0 + 1 < n) for (int p = o1 + v[1]; p < o2; p++) col[p] = n;
    if (i0 + 2 < n) for (int p = o2 + v[2]; p < o3; p++) col[p] = n;
    if (i0 + 3 < n) for (int p = o3 + v[3]; p < o4; p++) col[p] = n;
}

// ---- fused: XCD-partitioned CSR scatter (blocks < CSRB) + gemm1 (rest) ----
// csr: part = blockIdx%8 handles dsts with dst>>13 == part over a 2048-edge
// chunk. Writes to col land in one partition's contiguous region -> one XCD's
// L2 accumulates full lines (heuristic: consecutive blockIdx round-robin XCDs).
#define CSR_CHUNK 2048
__global__ __launch_bounds__(256) void k_csrgemm(const int* __restrict__ src,
                                                 const int* __restrict__ dst,
                                                 int* __restrict__ fill2,
                                                 int* __restrict__ col, int E, int CSRB,
                                                 const float* __restrict__ A,
                                                 const __bf16* __restrict__ Wp_hi,
                                                 const __bf16* __restrict__ Wp_lo,
                                                 const float* __restrict__ dinv,
                                                 __bf16* __restrict__ Cbf, int n) {
    int b = blockIdx.x;
    if (b < CSRB) {
        int part = b & 7;
        int e0 = (b >> 3) * CSR_CHUNK;
        int e1 = e0 + CSR_CHUNK;
        if (e1 > E) e1 = E;
        for (int e = e0 + threadIdx.x; e < e1; e += 256) {
            int d = dst[e];
            if ((d >> 13) == part) {
                int pos = atomicAdd(&fill2[d], 1);
                col[pos] = src[e];
            }
        }
        return;
    }
    // ---- gemm1: fp32 A, hi/lo split, 3 mfma per K-chunk; epilogue *dinv ----
    constexpr int NT = 8;
    constexpr int N = NT * 16;
    int bid = b - CSRB;
    int wave = bid * 4 + (int)(threadIdx.x >> 6);
    int lane = threadIdx.x & 63;
    int row0 = wave * 16;
    if (row0 >= n) return;
    int m = lane & 15;
    int q = lane >> 4;
    int row = row0 + m;
    if (row >= n) row = n - 1;
    const float* ap = A + (size_t)row * 128 + q * 8;
    bf16x8 ahi[4], alo[4];
#pragma unroll
    for (int c = 0; c < 4; c++) {
        float4 v0 = *(const float4*)(ap + c * 32);
        float4 v1 = *(const float4*)(ap + c * 32 + 4);
        float vv[8] = {v0.x, v0.y, v0.z, v0.w, v1.x, v1.y, v1.z, v1.w};
#pragma unroll
        for (int j = 0; j < 8; j++) {
            __bf16 h = (__bf16)vv[j];
            ahi[c][j] = h;
            alo[c][j] = (__bf16)(vv[j] - (float)h);
        }
    }
    float dscale[4];
#pragma unroll
    for (int r = 0; r < 4; r++) {
        int rr = row0 + q * 4 + r;
        dscale[r] = dinv[rr < n ? rr : (n - 1)];
    }
#pragma unroll
    for (int t = 0; t < NT; t++) {
        f32x4 acc = {0.f, 0.f, 0.f, 0.f};
#pragma unroll
        for (int c = 0; c < 4; c++) {
            size_t off = ((size_t)(t * 4 + c) * 64 + lane) * 8;
            bf16x8 bh = *(const bf16x8*)(Wp_hi + off);
            bf16x8 bl = *(const bf16x8*)(Wp_lo + off);
            acc = __builtin_amdgcn_mfma_f32_16x16x32_bf16(ahi[c], bh, acc, 0, 0, 0);
            acc = __builtin_amdgcn_mfma_f32_16x16x32_bf16(alo[c], bh, acc, 0, 0, 0);
            acc = __builtin_amdgcn_mfma_f32_16x16x32_bf16(ahi[c], bl, acc, 0, 0, 0);
        }
        int colx = t * 16 + m;
#pragma unroll
        for (int r = 0; r < 4; r++) {
            int orow = row0 + q * 4 + r;
            if (orow < n) Cbf[(size_t)orow * N + colx] = (__bf16)(acc[r] * dscale[r]);
        }
    }
}

// ---------------- bf16-A MFMA GEMM (layers 2/3), epilogue *dinv ----------------
template <int NT>
__global__ __launch_bounds__(256) void k_gemm_bf16(const __bf16* __restrict__ A,
                                                   const __bf16* __restrict__ Wp_hi,
                                                   const __bf16* __restrict__ Wp_lo,
                                                   const float* __restrict__ dinv,
                                                   __bf16* __restrict__ Cbf, int n) {
    constexpr int N = NT * 16;
    int wave = (int)((blockIdx.x * 256u + threadIdx.x) >> 6);
    int lane = threadIdx.x & 63;
    int row0 = wave * 16;
    if (row0 >= n) return;
    int m = lane & 15;
    int q = lane >> 4;
    int row = row0 + m;
    if (row >= n) row = n - 1;
    const __bf16* ap = A + (size_t)row * 128 + q * 8;
    bf16x8 a[4];
#pragma unroll
    for (int c = 0; c < 4; c++) a[c] = *(const bf16x8*)(ap + c * 32);
    float dscale[4];
#pragma unroll
    for (int r = 0; r < 4; r++) {
        int rr = row0 + q * 4 + r;
        dscale[r] = dinv[rr < n ? rr : (n - 1)];
    }
#pragma unroll
    for (int t = 0; t < NT; t++) {
        f32x4 acc = {0.f, 0.f, 0.f, 0.f};
#pragma unroll
        for (int c = 0; c < 4; c++) {
            size_t off = ((size_t)(t * 4 + c) * 64 + lane) * 8;
            bf16x8 bh = *(const bf16x8*)(Wp_hi + off);
            bf16x8 bl = *(const bf16x8*)(Wp_lo + off);
            acc = __builtin_amdgcn_mfma_f32_16x16x32_bf16(a[c], bh, acc, 0, 0, 0);
            acc = __builtin_amdgcn_mfma_f32_16x16x32_bf16(a[c], bl, acc, 0, 0, 0);
        }
        int colx = t * 16 + m;
#pragma unroll
        for (int r = 0; r < 4; r++) {
            int orow = row0 + q * 4 + r;
            if (orow < n) Cbf[(size_t)orow * N + colx] = (__bf16)(acc[r] * dscale[r]);
        }
    }
}

// ---------------- aggregation: pure gather-sum; rows are k x 16 slots ----------------
__global__ __launch_bounds__(256) void k_agg128(const unsigned int* __restrict__ t32,
                                                const int* __restrict__ rowptr,
                                                const int* __restrict__ col,
                                                const float* __restrict__ dinv,
                                                const float* __restrict__ bias,
                                                unsigned int* __restrict__ out, int n) {
    int w = (int)((blockIdx.x * 256u + threadIdx.x) >> 6);
    int lane = threadIdx.x & 63;
    if (w >= n) return;
    unsigned us = t32[(size_t)w * 64 + lane];
    float a0 = bflo(us);
    float a1 = bfhi(us);
    int p = rowptr[w], pe = rowptr[w + 1];
    for (; p < pe; p += 16) {  // row length is a multiple of 16: all gathers in flight
        int4 c0 = *(const int4*)(col + p);
        int4 c1 = *(const int4*)(col + p + 4);
        int4 c2 = *(const int4*)(col + p + 8);
        int4 c3 = *(const int4*)(col + p + 12);
        unsigned u0 = t32[((size_t)c0.x << 6) + lane];
        unsigned u1 = t32[((size_t)c0.y << 6) + lane];
        unsigned u2 = t32[((size_t)c0.z << 6) + lane];
        unsigned u3 = t32[((size_t)c0.w << 6) + lane];
        unsigned u4 = t32[((size_t)c1.x << 6) + lane];
        unsigned u5 = t32[((size_t)c1.y << 6) + lane];
        unsigned u6 = t32[((size_t)c1.z << 6) + lane];
        unsigned u7 = t32[((size_t)c1.w << 6) + lane];
        unsigned u8 = t32[((size_t)c2.x << 6) + lane];
        unsigned u9 = t32[((size_t)c2.y << 6) + lane];
        unsigned ua = t32[((size_t)c2.z << 6) + lane];
        unsigned ub = t32[((size_t)c2.w << 6) + lane];
        unsigned uc = t32[((size_t)c3.x << 6) + lane];
        unsigned ud = t32[((size_t)c3.y << 6) + lane];
        unsigned ue = t32[((size_t)c3.z << 6) + lane];
        unsigned uf = t32[((size_t)c3.w << 6) + lane];
        a0 += bflo(u0); a1 += bfhi(u0);
        a0 += bflo(u1); a1 += bfhi(u1);
        a0 += bflo(u2); a1 += bfhi(u2);
        a0 += bflo(u3); a1 += bfhi(u3);
        a0 += bflo(u4); a1 += bfhi(u4);
        a0 += bflo(u5); a1 += bfhi(u5);
        a0 += bflo(u6); a1 += bfhi(u6);
        a0 += bflo(u7); a1 += bfhi(u7);
        a0 += bflo(u8); a1 += bfhi(u8);
        a0 += bflo(u9); a1 += bfhi(u9);
        a0 += bflo(ua); a1 += bfhi(ua);
        a0 += bflo(ub); a1 += bfhi(ub);
        a0 += bflo(uc); a1 += bfhi(uc);
        a0 += bflo(ud); a1 += bfhi(ud);
        a0 += bflo(ue); a1 += bfhi(ue);
        a0 += bflo(uf); a1 += bfhi(uf);
    }
    float di = dinv[w];
    BF2 o;
    o.h[0] = (__bf16)fmaxf(di * a0 + bias[lane * 2], 0.f);
    o.h[1] = (__bf16)fmaxf(di * a1 + bias[lane * 2 + 1], 0.f);
    out[(size_t)w * 64 + lane] = o.u;
}

__global__ __launch_bounds__(256) void k_agg64(const unsigned short* __restrict__ t16,
                                               const int* __restrict__ rowptr,
                                               const int* __restrict__ col,
                                               const float* __restrict__ dinv,
                                               const float* __restrict__ bias,
                                               __bf16* __restrict__ out, int n) {
    int w = (int)((blockIdx.x * 256u + threadIdx.x) >> 6);
    int lane = threadIdx.x & 63;
    if (w >= n) return;
    float acc = __uint_as_float((unsigned)t16[(size_t)w * 64 + lane] << 16);
    int p = rowptr[w], pe = rowptr[w + 1];
    for (; p < pe; p += 16) {
        int4 c0 = *(const int4*)(col + p);
        int4 c1 = *(const int4*)(col + p + 4);
        int4 c2 = *(const int4*)(col + p + 8);
        int4 c3 = *(const int4*)(col + p + 12);
        unsigned u0 = t16[((size_t)c0.x << 6) + lane];
        unsigned u1 = t16[((size_t)c0.y << 6) + lane];
        unsigned u2 = t16[((size_t)c0.z << 6) + lane];
        unsigned u3 = t16[((size_t)c0.w << 6) + lane];
        unsigned u4 = t16[((size_t)c1.x << 6) + lane];
        unsigned u5 = t16[((size_t)c1.y << 6) + lane];
        unsigned u6 = t16[((size_t)c1.z << 6) + lane];
        unsigned u7 = t16[((size_t)c1.w << 6) + lane];
        unsigned u8 = t16[((size_t)c2.x << 6) + lane];
        unsigned u9 = t16[((size_t)c2.y << 6) + lane];
        unsigned ua = t16[((size_t)c2.z << 6) + lane];
        unsigned ub = t16[((size_t)c2.w << 6) + lane];
        unsigned uc = t16[((size_t)c3.x << 6) + lane];
        unsigned ud = t16[((size_t)c3.y << 6) + lane];
        unsigned ue = t16[((size_t)c3.z << 6) + lane];
        unsigned uf = t16[((size_t)c3.w << 6) + lane];
        acc += __uint_as_float(u0 << 16);
        acc += __uint_as_float(u1 << 16);
        acc += __uint_as_float(u2 << 16);
        acc += __uint_as_float(u3 << 16);
        acc += __uint_as_float(u4 << 16);
        acc += __uint_as_float(u5 << 16);
        acc += __uint_as_float(u6 << 16);
        acc += __uint_as_float(u7 << 16);
        acc += __uint_as_float(u8 << 16);
        acc += __uint_as_float(u9 << 16);
        acc += __uint_as_float(ua << 16);
        acc += __uint_as_float(ub << 16);
        acc += __uint_as_float(uc << 16);
        acc += __uint_as_float(ud << 16);
        acc += __uint_as_float(ue << 16);
        acc += __uint_as_float(uf << 16);
    }
    out[(size_t)w * 64 + lane] = (__bf16)fmaxf(dinv[w] * acc + bias[lane], 0.f);
}

// ---------------- fused mean-pool + MLP head ----------------
__global__ __launch_bounds__(256) void k_poolmlp(const unsigned short* __restrict__ h,
                                                 const int* __restrict__ gstart,
                                                 const float* __restrict__ demo,
                                                 const float* __restrict__ Wf1,
                                                 const float* __restrict__ bf1,
                                                 const float* __restrict__ Wf2,
                                                 const float* __restrict__ bf2,
                                                 const float* __restrict__ Wf3,
                                                 const float* __restrict__ bf3,
                                                 float* __restrict__ out, int G) {
    int g = blockIdx.x;
    int tid = threadIdx.x;
    int lane = tid & 63;
    int wv = tid >> 6;
    int s = gstart[g], e = gstart[g + 1];
    float acc = 0.f;
    for (int i = s + wv; i < e; i += 4)
        acc += __uint_as_float((unsigned)h[(size_t)i * 64 + lane] << 16);
    __shared__ float red[4][64];
    __shared__ float zin[72];
    __shared__ float z1[64];
    __shared__ float z2[32];
    red[wv][lane] = acc;
    if (tid >= 64 && tid < 72) zin[tid] = demo[g * 8 + (tid - 64)];
    __syncthreads();
    if (tid < 64) {
        float v = red[0][tid] + red[1][tid] + red[2][tid] + red[3][tid];
        zin[tid] = v / fmaxf((float)(e - s), 1.0f);
    }
    __syncthreads();
    if (tid < 64) {
        float a = bf1[tid];
        for (int k = 0; k < 72; k++) a += zin[k] * Wf1[k * 64 + tid];
        z1[tid] = fmaxf(a, 0.f);
    }
    __syncthreads();
    if (tid < 32) {
        float a2 = bf2[tid];
        for (int k = 0; k < 64; k++) a2 += z1[k] * Wf2[k * 32 + tid];
        z2[tid] = fmaxf(a2, 0.f);
    }
    __syncthreads();
    if (tid < 2) {
        float a3 = bf3[tid];
        for (int k = 0; k < 32; k++) a3 += z2[k] * Wf3[k * 2 + tid];
        out[g * 2 + tid] = a3;
    }
}

extern "C" void kernel_launch(void* const* d_in, const int* in_sizes, int n_in,
                              void* d_out, int out_size, void* d_ws, size_t ws_size,
                              hipStream_t stream) {
    const float* x    = (const float*)d_in[0];
    const int*   ei   = (const int*)d_in[1];
    const int*   batch= (const int*)d_in[2];
    const float* demo = (const float*)d_in[3];
    const float* W1   = (const float*)d_in[4];
    const float* b1   = (const float*)d_in[5];
    const float* W2   = (const float*)d_in[6];
    const float* b2   = (const float*)d_in[7];
    const float* W3   = (const float*)d_in[8];
    const float* b3   = (const float*)d_in[9];
    const float* Wf1  = (const float*)d_in[10];
    const float* bf1  = (const float*)d_in[11];
    const float* Wf2  = (const float*)d_in[12];
    const float* bf2  = (const float*)d_in[13];
    const float* Wf3  = (const float*)d_in[14];
    const float* bf3  = (const float*)d_in[15];
    float* out = (float*)d_out;

    const int n = in_sizes[0] / 128;  // 50000
    const int E = in_sizes[1] / 2;    // 600000
    const int G = in_sizes[3] / 8;    // 100
    const int Epad = E + 15 * n;      // worst-case padded CSR size (pad to 16)
    const int nchunks = (n + 4095) / 4096;

    char* ws = (char*)d_ws;
    auto alloc = [&](size_t bytes) {
        char* p = ws;
        ws += (bytes + 255) & ~(size_t)255;
        return p;
    };
    int*    cnt    = (int*)alloc((size_t)n * 4);
    float*  dinv   = (float*)alloc((size_t)n * 4);
    int*    rowptr = (int*)alloc((size_t)(n + 1) * 4);
    int*    fill2  = (int*)alloc((size_t)n * 4);
    int*    partial= (int*)alloc((size_t)nchunks * 4);
    int*    col    = (int*)alloc((size_t)Epad * 4);
    __bf16* tbf    = (__bf16*)alloc((size_t)(n + 1) * 128 * 2);  // ts (layers 1/2), row n = 0
    __bf16* hbuf   = (__bf16*)alloc((size_t)n * 128 * 2);        // agg out bf16
    __bf16* t3bf   = (__bf16*)alloc((size_t)(n + 1) * 64 * 2);   // ts layer 3, row n = 0
    __bf16* h3     = (__bf16*)alloc((size_t)n * 64 * 2);         // agg3 out (bf16)
    __bf16* Wp1h   = (__bf16*)alloc(128 * 128 * 2);
    __bf16* Wp1l   = (__bf16*)alloc(128 * 128 * 2);
    __bf16* Wp2h   = (__bf16*)alloc(128 * 128 * 2);
    __bf16* Wp2l   = (__bf16*)alloc(128 * 128 * 2);
    __bf16* Wp3h   = (__bf16*)alloc(128 * 64 * 2);
    __bf16* Wp3l   = (__bf16*)alloc(128 * 64 * 2);
    int*    gstart = (int*)alloc((size_t)(G + 1) * 4);

    const int* srcv = ei;
    const int* dstv = ei + E;

    hipMemsetAsync(cnt, 0, (size_t)n * 4, stream);

    const int EB = (E + 255) / 256;
    // k_pre: EB degree blocks + 1 gstart block + 20 wpack blocks (W1,W2,W3)
    k_pre<<<EB + 21, 256, 0, stream>>>(dstv, cnt, batch, gstart, W1, Wp1h, Wp1l,
                                       W2, W3, Wp2h, Wp2l, Wp3h, Wp3l, E, n, G, EB);
    // parallel scan: partial sums -> per-chunk scan + writes
    k_sum<<<nchunks, 1024, 0, stream>>>(cnt, partial, dinv,
                                        (unsigned int*)tbf, (unsigned int*)t3bf, n);
    k_out<<<nchunks, 1024, 0, stream>>>(cnt, partial, rowptr, fill2, col, n, nchunks);

    int waves = (n + 15) / 16;
    int gemm_blocks = (waves + 3) / 4;
    int agg_blocks = (int)(((size_t)n * 64 + 255) / 256);

    // fused: XCD-partitioned CSR scatter || gemm1 (independent after k_out)
    const int CSRB = 8 * ((E + CSR_CHUNK - 1) / CSR_CHUNK);
    k_csrgemm<<<CSRB + gemm_blocks, 256, 0, stream>>>(srcv, dstv, fill2, col, E, CSRB,
                                                      x, Wp1h, Wp1l, dinv, tbf, n);

    // Layer 1 aggregation
    k_agg128<<<agg_blocks, 256, 0, stream>>>((const unsigned int*)tbf, rowptr, col,
                                             dinv, b1, (unsigned int*)hbuf, n);
    // Layer 2
    k_gemm_bf16<8><<<gemm_blocks, 256, 0, stream>>>(hbuf, Wp2h, Wp2l, dinv, tbf, n);
    k_agg128<<<agg_blocks, 256, 0, stream>>>((const unsigned int*)tbf, rowptr, col,
                                             dinv, b2, (unsigned int*)hbuf, n);
    // Layer 3 (128 -> 64)
    k_gemm_bf16<4><<<gemm_blocks, 256, 0, stream>>>(hbuf, Wp3h, Wp3l, dinv, t3bf, n);
    k_agg64<<<agg_blocks, 256, 0, stream>>>((const unsigned short*)t3bf, rowptr, col,
                                            dinv, b3, h3, n);

    k_poolmlp<<<G, 256, 0, stream>>>((const unsigned short*)h3, gstart, demo,
                                     Wf1, bf1, Wf2, bf2, Wf3, bf3, out, G);
}

// Round 15
// 289.341 us; speedup vs baseline: 1.0862x; 1.0862x over previous
//
#include <hip/hip_runtime.h>

// ---------------------------------------------------------------------------
// ROIAwareGCN: 3x GCNConv + mean-pool + MLP.
// R1: atomic pool -> segmented reduction. R2: split-bf16 MFMA GEMM, bf16 t.
// R3: padded CSR. R4: pool+mlp fused. R5/R6: single-block scan.
// R7: bucket atomics REGRESSED. R8: LDS sort CRASHED. R9: col-only NEUTRAL.
// R10: wgt[] eliminated (dinv in GEMM epilogue; pad cols -> zero row n).
// R11: scan split into k_sum/k_out. R12: pad-16 NEUTRAL (aggs throughput-bound).
// R13: XCD-partition filter NEUTRAL -- blockIdx%8->XCD mapping assumption
//      doesn't hold; scattered 4B col stores still cost a 64B coherence line.
// R14: col writes made block-owned: k_bin3 appends edges into block-PRIVATE
//      (chunk,bucket) regions via LDS cursors (zero global atomics; lines
//      merge in one XCD's L2); k_csr3 (block per bucket) reads all entries in
//      2 parallel rounds (prefix + binary search -- no serial chunk chain),
//      places via per-row LDS cursors into n-initialized staging (pads free),
//      writes col fully coalesced. All LDS indices bounds-guarded; size>LDS
//      falls back to the proven global-cursor scatter. CAP=64 per cell
//      (Poisson 10.5; P(overflow)~1e-30, clamp-skip so no fault possible).
// ---------------------------------------------------------------------------

typedef __bf16 bf16x8 __attribute__((ext_vector_type(8)));
typedef float f32x4 __attribute__((ext_vector_type(4)));

__device__ __forceinline__ float bflo(unsigned u) { return __uint_as_float(u << 16); }
__device__ __forceinline__ float bfhi(unsigned u) { return __uint_as_float(u & 0xffff0000u); }

union BF2 {
    __bf16 h[2];
    unsigned u;
};

#define PAD(c) (((c) + 15) & ~15)
#define BCAP 64
#define ECHUNK 4096

// ---------------- W pre-pack into MFMA B-fragment layout ----------------
__device__ __forceinline__ void wpack_block(const float* __restrict__ W,
                                            __bf16* __restrict__ hi,
                                            __bf16* __restrict__ lo, int N, int b, int l) {
    int t = b >> 2, c = b & 3;
    int k0 = c * 32 + (l >> 4) * 8;
    int ncol = t * 16 + (l & 15);
    size_t base = ((size_t)b * 64 + l) * 8;
#pragma unroll
    for (int j = 0; j < 8; j++) {
        float v = W[(size_t)(k0 + j) * N + ncol];
        __bf16 h = (__bf16)v;
        hi[base + j] = h;
        lo[base + j] = (__bf16)(v - (float)h);
    }
}

// ---- fused: degree count + graph boundaries + wpack(W1,W2,W3) ----
__global__ void k_pre(const int* __restrict__ dst, int* __restrict__ cnt,
                      const int* __restrict__ batch, int* __restrict__ gstart,
                      const float* __restrict__ W1, __bf16* __restrict__ Wp1h,
                      __bf16* __restrict__ Wp1l,
                      const float* __restrict__ W2, const float* __restrict__ W3,
                      __bf16* __restrict__ Wp2h, __bf16* __restrict__ Wp2l,
                      __bf16* __restrict__ Wp3h, __bf16* __restrict__ Wp3l,
                      int E, int n, int G, int EB) {
    int b = blockIdx.x;
    if (b < EB) {
        int e = b * 256 + threadIdx.x;
        if (e < E) atomicAdd(&cnt[dst[e]], 1);
    } else if (b == EB) {
        int g = threadIdx.x;
        if (g <= G) {
            int lo = 0, hi = n;
            while (lo < hi) {
                int mid = (lo + hi) >> 1;
                if (batch[mid] < g) lo = mid + 1; else hi = mid;
            }
            gstart[g] = lo;  // lower_bound: first i with batch[i] >= g
        }
    } else {
        int b64 = (b - EB - 1) * 4 + (threadIdx.x >> 6);  // 0..79
        int l = threadIdx.x & 63;
        if (b64 < 32) wpack_block(W1, Wp1h, Wp1l, 128, b64, l);
        else if (b64 < 64) wpack_block(W2, Wp2h, Wp2l, 128, b64 - 32, l);
        else if (b64 < 80) wpack_block(W3, Wp3h, Wp3l, 64, b64 - 64, l);
    }
}

// ---------------- scan stage 1: per-chunk padded sums + dinv ----------------
__global__ __launch_bounds__(1024) void k_sum(const int* __restrict__ cnt,
                                              int* __restrict__ partial,
                                              float* __restrict__ dinv,
                                              unsigned int* __restrict__ tz128,
                                              unsigned int* __restrict__ tz64, int n) {
    __shared__ int ws[16];
    int b = blockIdx.x;
    int tid = threadIdx.x;
    int lane = tid & 63;
    int wid = tid >> 6;
    if (b == 0) {  // zero row n of the two gather targets
        if (tid < 64) tz128[(size_t)n * 64 + tid] = 0u;
        else if (tid < 96) tz64[(size_t)n * 32 + (tid - 64)] = 0u;
    }
    int i0 = (b << 12) + tid * 4;
    int s = 0;
    if (i0 + 3 < n) {
        int4 v = *(const int4*)(cnt + i0);
        float4 dv;
        dv.x = rsqrtf((float)(v.x + 1));
        dv.y = rsqrtf((float)(v.y + 1));
        dv.z = rsqrtf((float)(v.z + 1));
        dv.w = rsqrtf((float)(v.w + 1));
        *(float4*)(dinv + i0) = dv;
        s = PAD(v.x) + PAD(v.y) + PAD(v.z) + PAD(v.w);
    } else if (i0 < n) {
#pragma unroll
        for (int j = 0; j < 4; j++) {
            if (i0 + j < n) {
                int v = cnt[i0 + j];
                dinv[i0 + j] = rsqrtf((float)(v + 1));
                s += PAD(v);
            }
        }
    }
#pragma unroll
    for (int d = 32; d > 0; d >>= 1) s += __shfl_xor(s, d);
    if (lane == 0) ws[wid] = s;
    __syncthreads();
    if (tid == 0) {
        int t = 0;
#pragma unroll
        for (int k = 0; k < 16; k++) t += ws[k];
        partial[b] = t;
    }
}

// ---------------- scan stage 2: rowptr/fill2 (no pad-col writes) ----------------
__global__ __launch_bounds__(1024) void k_out(const int* __restrict__ cnt,
                                              const int* __restrict__ partial,
                                              int* __restrict__ rowptr,
                                              int* __restrict__ fill2,
                                              int n, int nchunks) {
    __shared__ int lsum[16];
    __shared__ int base_s;
    int b = blockIdx.x;
    int tid = threadIdx.x;
    int lane = tid & 63;
    int wid = tid >> 6;
    if (tid == 0) {
        int acc = 0;
        for (int c = 0; c < b; c++) acc += partial[c];
        base_s = acc;
    }
    if (b == 0 && tid == 1) {
        int acc = 0;
        for (int c = 0; c < nchunks; c++) acc += partial[c];
        rowptr[n] = acc;
    }
    int i0 = (b << 12) + tid * 4;
    int v[4], pv[4];
    int s = 0;
    if (i0 < n) {
        if (i0 + 3 < n) {
            int4 vv = *(const int4*)(cnt + i0);
            v[0] = vv.x; v[1] = vv.y; v[2] = vv.z; v[3] = vv.w;
        } else {
#pragma unroll
            for (int j = 0; j < 4; j++) v[j] = (i0 + j < n) ? cnt[i0 + j] : 0;
        }
    } else {
#pragma unroll
        for (int j = 0; j < 4; j++) v[j] = 0;
    }
#pragma unroll
    for (int j = 0; j < 4; j++) {
        pv[j] = PAD(v[j]);
        s += pv[j];
    }
    int sc = s;
#pragma unroll
    for (int d = 1; d < 64; d <<= 1) {
        int o = __shfl_up(sc, d);
        if (lane >= d) sc += o;
    }
    int exc = sc - s;
    if (lane == 63) lsum[wid] = sc;
    __syncthreads();
    if (wid == 0) {
        int val = (lane < 16) ? lsum[lane] : 0;
        int sc2 = val;
#pragma unroll
        for (int d = 1; d < 16; d <<= 1) {
            int o = __shfl_up(sc2, d);
            if (lane >= d) sc2 += o;
        }
        if (lane < 16) lsum[lane] = sc2 - val;
    }
    __syncthreads();
    if (i0 >= n) return;
    int off = base_s + lsum[wid] + exc;
    int o0 = off;
    int o1 = o0 + pv[0];
    int o2 = o1 + pv[1];
    int o3 = o2 + pv[2];
    if (i0 + 3 < n) {
        int4 ov = {o0, o1, o2, o3};
        *(int4*)(rowptr + i0) = ov;
        *(int4*)(fill2 + i0) = ov;
    } else {
        int oo[4] = {o0, o1, o2, o3};
#pragma unroll
        for (int j = 0; j < 4; j++) {
            if (i0 + j < n) {
                rowptr[i0 + j] = oo[j];
                fill2[i0 + j] = oo[j];
            }
        }
    }
}

// ---- phase 1: block-private binning (blocks < EC) + gemm1 tail (rest) ----
// Each chunk block appends its 4096 edges into private (chunk,bucket) regions
// via LDS cursors. No global atomics; single-writer regions merge in L2.
__global__ __launch_bounds__(1024) void k_bin3(const int* __restrict__ src,
                                               const int* __restrict__ dst,
                                               int2* __restrict__ binbuf,
                                               int* __restrict__ bcnt,
                                               int E, int EC, int nbuck,
                                               const float* __restrict__ A,
                                               const __bf16* __restrict__ Wp_hi,
                                               const __bf16* __restrict__ Wp_lo,
                                               const float* __restrict__ dinv,
                                               __bf16* __restrict__ Cbf, int n) {
    int b = blockIdx.x;
    int tid = threadIdx.x;
    if (b < EC) {
        __shared__ int lcur[512];
        for (int i = tid; i < nbuck; i += 1024) lcur[i] = 0;
        __syncthreads();
        int e0 = b * ECHUNK;
        int cntE = E - e0;
        if (cntE > ECHUNK) cntE = ECHUNK;
#pragma unroll
        for (int k = 0; k < 4; k++) {
            int idx = tid + k * 1024;
            if (idx < cntE) {
                int s = src[e0 + idx];
                int d = dst[e0 + idx];
                int bk = d >> 7;  // d in [0,n) -> bk < nbuck
                int slot = atomicAdd(&lcur[bk], 1);
                if (slot < BCAP) {
                    int2 sd = {s, d};
                    binbuf[((size_t)b * nbuck + bk) * BCAP + slot] = sd;
                }
            }
        }
        __syncthreads();
        for (int bk = tid; bk < nbuck; bk += 1024) {
            int c = lcur[bk];
            bcnt[b * nbuck + bk] = (c < BCAP) ? c : BCAP;
        }
        return;
    }
    // ---- gemm1 tail: fp32 A, hi/lo split, 3 mfma per K-chunk; *dinv ----
    constexpr int NT = 8;
    constexpr int N = NT * 16;
    int bid = b - EC;
    int wave = bid * 16 + (tid >> 6);
    int lane = tid & 63;
    int row0 = wave * 16;
    if (row0 >= n) return;
    int m = lane & 15;
    int q = lane >> 4;
    int row = row0 + m;
    if (row >= n) row = n - 1;
    const float* ap = A + (size_t)row * 128 + q * 8;
    bf16x8 ahi[4], alo[4];
#pragma unroll
    for (int c = 0; c < 4; c++) {
        float4 v0 = *(const float4*)(ap + c * 32);
        float4 v1 = *(const float4*)(ap + c * 32 + 4);
        float vv[8] = {v0.x, v0.y, v0.z, v0.w, v1.x, v1.y, v1.z, v1.w};
#pragma unroll
        for (int j = 0; j < 8; j++) {
            __bf16 h = (__bf16)vv[j];
            ahi[c][j] = h;
            alo[c][j] = (__bf16)(vv[j] - (float)h);
        }
    }
    float dscale[4];
#pragma unroll
    for (int r = 0; r < 4; r++) {
        int rr = row0 + q * 4 + r;
        dscale[r] = dinv[rr < n ? rr : (n - 1)];
    }
#pragma unroll
    for (int t = 0; t < NT; t++) {
        f32x4 acc = {0.f, 0.f, 0.f, 0.f};
#pragma unroll
        for (int c = 0; c < 4; c++) {
            size_t off = ((size_t)(t * 4 + c) * 64 + lane) * 8;
            bf16x8 bh = *(const bf16x8*)(Wp_hi + off);
            bf16x8 bl = *(const bf16x8*)(Wp_lo + off);
            acc = __builtin_amdgcn_mfma_f32_16x16x32_bf16(ahi[c], bh, acc, 0, 0, 0);
            acc = __builtin_amdgcn_mfma_f32_16x16x32_bf16(alo[c], bh, acc, 0, 0, 0);
            acc = __builtin_amdgcn_mfma_f32_16x16x32_bf16(ahi[c], bl, acc, 0, 0, 0);
        }
        int colx = t * 16 + m;
#pragma unroll
        for (int r = 0; r < 4; r++) {
            int orow = row0 + q * 4 + r;
            if (orow < n) Cbf[(size_t)orow * N + colx] = (__bf16)(acc[r] * dscale[r]);
        }
    }
}

// ---- phase 2: block per bucket -> staged CSR, coalesced col writeout ----
__global__ __launch_bounds__(1024) void k_csr3(const int2* __restrict__ binbuf,
                                               const int* __restrict__ bcnt,
                                               const int* __restrict__ rowptr,
                                               int* __restrict__ fill2,
                                               int* __restrict__ col,
                                               int n, int EC, int nbuck) {
    __shared__ int cols_s[5120];
    __shared__ int lcnt[160];
    __shared__ int lpre[161];
    __shared__ int lfill[128];
    int b = blockIdx.x;
    int tid = threadIdx.x;
    int lane = tid & 63;
    int wid = tid >> 6;
    int r0 = b << 7;
    int r1 = r0 + 128;
    if (r1 > n) r1 = n;
    int nrows = r1 - r0;
    int base = rowptr[r0];
    int end = rowptr[r1];
    int size = end - base;

    for (int c = tid; c < EC; c += 1024) lcnt[c] = bcnt[c * nbuck + b];
    if (tid < nrows) lfill[tid] = rowptr[r0 + tid] - base;
    __syncthreads();

    // wave 0: exclusive scan of lcnt[0..EC) -> lpre, total in lpre[EC]
    if (wid == 0) {
        int carry = 0;
        for (int bb = 0; bb < EC; bb += 64) {
            int idx = bb + lane;
            int val = (idx < EC) ? lcnt[idx] : 0;
            int sc = val;
#pragma unroll
            for (int d = 1; d < 64; d <<= 1) {
                int o = __shfl_up(sc, d);
                if (lane >= d) sc += o;
            }
            int grp = __shfl(sc, 63);
            if (idx < EC) lpre[idx] = sc - val + carry;
            carry += grp;
        }
        if (lane == 0) lpre[EC] = carry;
    }
    if (size <= 5120) {
        for (int i = tid; i < size; i += 1024) cols_s[i] = n;  // pads -> zero row
        __syncthreads();
        int T = lpre[EC];
        for (int i = tid; i < T; i += 1024) {
            // binary search: largest c with lpre[c] <= i
            int lo = 0, hi = EC;
            while (lo < hi) {
                int mid = (lo + hi) >> 1;
                if (lpre[mid + 1] <= i) lo = mid + 1; else hi = mid;
            }
            int j = i - lpre[lo];
            int2 sd = binbuf[((size_t)lo * nbuck + b) * BCAP + j];
            unsigned r = (unsigned)(sd.y - r0);
            if (r < (unsigned)nrows) {
                int pos = atomicAdd(&lfill[r], 1);
                if ((unsigned)pos < (unsigned)size) cols_s[pos] = sd.x;
            }
        }
        __syncthreads();
        for (int i = tid; i < size; i += 1024) col[base + i] = cols_s[i];
    } else {
        // fallback: direct global placement (fill2 = rowptr copy)
        for (int i = tid; i < size; i += 1024) col[base + i] = n;
        __syncthreads();
        int T = lpre[EC];
        for (int i = tid; i < T; i += 1024) {
            int lo = 0, hi = EC;
            while (lo < hi) {
                int mid = (lo + hi) >> 1;
                if (lpre[mid + 1] <= i) lo = mid + 1; else hi = mid;
            }
            int j = i - lpre[lo];
            int2 sd = binbuf[((size_t)lo * nbuck + b) * BCAP + j];
            unsigned r = (unsigned)(sd.y - r0);
            if (r < (unsigned)nrows) {
                int pos = atomicAdd(&fill2[sd.y], 1);
                if (pos >= base && pos < end) col[pos] = sd.x;
            }
        }
    }
}

// ---------------- bf16-A MFMA GEMM (layers 2/3), epilogue *dinv ----------------
template <int NT>
__global__ __launch_bounds__(256) void k_gemm_bf16(const __bf16* __restrict__ A,
                                                   const __bf16* __restrict__ Wp_hi,
                                                   const __bf16* __restrict__ Wp_lo,
                                                   const float* __restrict__ dinv,
                                                   __bf16* __restrict__ Cbf, int n) {
    constexpr int N = NT * 16;
    int wave = (int)((blockIdx.x * 256u + threadIdx.x) >> 6);
    int lane = threadIdx.x & 63;
    int row0 = wave * 16;
    if (row0 >= n) return;
    int m = lane & 15;
    int q = lane >> 4;
    int row = row0 + m;
    if (row >= n) row = n - 1;
    const __bf16* ap = A + (size_t)row * 128 + q * 8;
    bf16x8 a[4];
#pragma unroll
    for (int c = 0; c < 4; c++) a[c] = *(const bf16x8*)(ap + c * 32);
    float dscale[4];
#pragma unroll
    for (int r = 0; r < 4; r++) {
        int rr = row0 + q * 4 + r;
        dscale[r] = dinv[rr < n ? rr : (n - 1)];
    }
#pragma unroll
    for (int t = 0; t < NT; t++) {
        f32x4 acc = {0.f, 0.f, 0.f, 0.f};
#pragma unroll
        for (int c = 0; c < 4; c++) {
            size_t off = ((size_t)(t * 4 + c) * 64 + lane) * 8;
            bf16x8 bh = *(const bf16x8*)(Wp_hi + off);
            bf16x8 bl = *(const bf16x8*)(Wp_lo + off);
            acc = __builtin_amdgcn_mfma_f32_16x16x32_bf16(a[c], bh, acc, 0, 0, 0);
            acc = __builtin_amdgcn_mfma_f32_16x16x32_bf16(a[c], bl, acc, 0, 0, 0);
        }
        int colx = t * 16 + m;
#pragma unroll
        for (int r = 0; r < 4; r++) {
            int orow = row0 + q * 4 + r;
            if (orow < n) Cbf[(size_t)orow * N + colx] = (__bf16)(acc[r] * dscale[r]);
        }
    }
}

// ---------------- aggregation: pure gather-sum; rows are k x 16 slots ----------------
__global__ __launch_bounds__(256) void k_agg128(const unsigned int* __restrict__ t32,
                                                const int* __restrict__ rowptr,
                                                const int* __restrict__ col,
                                                const float* __restrict__ dinv,
                                                const float* __restrict__ bias,
                                                unsigned int* __restrict__ out, int n) {
    int w = (int)((blockIdx.x * 256u + threadIdx.x) >> 6);
    int lane = threadIdx.x & 63;
    if (w >= n) return;
    unsigned us = t32[(size_t)w * 64 + lane];
    float a0 = bflo(us);
    float a1 = bfhi(us);
    int p = rowptr[w], pe = rowptr[w + 1];
    for (; p < pe; p += 16) {
        int4 c0 = *(const int4*)(col + p);
        int4 c1 = *(const int4*)(col + p + 4);
        int4 c2 = *(const int4*)(col + p + 8);
        int4 c3 = *(const int4*)(col + p + 12);
        unsigned u0 = t32[((size_t)c0.x << 6) + lane];
        unsigned u1 = t32[((size_t)c0.y << 6) + lane];
        unsigned u2 = t32[((size_t)c0.z << 6) + lane];
        unsigned u3 = t32[((size_t)c0.w << 6) + lane];
        unsigned u4 = t32[((size_t)c1.x << 6) + lane];
        unsigned u5 = t32[((size_t)c1.y << 6) + lane];
        unsigned u6 = t32[((size_t)c1.z << 6) + lane];
        unsigned u7 = t32[((size_t)c1.w << 6) + lane];
        unsigned u8 = t32[((size_t)c2.x << 6) + lane];
        unsigned u9 = t32[((size_t)c2.y << 6) + lane];
        unsigned ua = t32[((size_t)c2.z << 6) + lane];
        unsigned ub = t32[((size_t)c2.w << 6) + lane];
        unsigned uc = t32[((size_t)c3.x << 6) + lane];
        unsigned ud = t32[((size_t)c3.y << 6) + lane];
        unsigned ue = t32[((size_t)c3.z << 6) + lane];
        unsigned uf = t32[((size_t)c3.w << 6) + lane];
        a0 += bflo(u0); a1 += bfhi(u0);
        a0 += bflo(u1); a1 += bfhi(u1);
        a0 += bflo(u2); a1 += bfhi(u2);
        a0 += bflo(u3); a1 += bfhi(u3);
        a0 += bflo(u4); a1 += bfhi(u4);
        a0 += bflo(u5); a1 += bfhi(u5);
        a0 += bflo(u6); a1 += bfhi(u6);
        a0 += bflo(u7); a1 += bfhi(u7);
        a0 += bflo(u8); a1 += bfhi(u8);
        a0 += bflo(u9); a1 += bfhi(u9);
        a0 += bflo(ua); a1 += bfhi(ua);
        a0 += bflo(ub); a1 += bfhi(ub);
        a0 += bflo(uc); a1 += bfhi(uc);
        a0 += bflo(ud); a1 += bfhi(ud);
        a0 += bflo(ue); a1 += bfhi(ue);
        a0 += bflo(uf); a1 += bfhi(uf);
    }
    float di = dinv[w];
    BF2 o;
    o.h[0] = (__bf16)fmaxf(di * a0 + bias[lane * 2], 0.f);
    o.h[1] = (__bf16)fmaxf(di * a1 + bias[lane * 2 + 1], 0.f);
    out[(size_t)w * 64 + lane] = o.u;
}

__global__ __launch_bounds__(256) void k_agg64(const unsigned short* __restrict__ t16,
                                               const int* __restrict__ rowptr,
                                               const int* __restrict__ col,
                                               const float* __restrict__ dinv,
                                               const float* __restrict__ bias,
                                               __bf16* __restrict__ out, int n) {
    int w = (int)((blockIdx.x * 256u + threadIdx.x) >> 6);
    int lane = threadIdx.x & 63;
    if (w >= n) return;
    float acc = __uint_as_float((unsigned)t16[(size_t)w * 64 + lane] << 16);
    int p = rowptr[w], pe = rowptr[w + 1];
    for (; p < pe; p += 16) {
        int4 c0 = *(const int4*)(col + p);
        int4 c1 = *(const int4*)(col + p + 4);
        int4 c2 = *(const int4*)(col + p + 8);
        int4 c3 = *(const int4*)(col + p + 12);
        unsigned u0 = t16[((size_t)c0.x << 6) + lane];
        unsigned u1 = t16[((size_t)c0.y << 6) + lane];
        unsigned u2 = t16[((size_t)c0.z << 6) + lane];
        unsigned u3 = t16[((size_t)c0.w << 6) + lane];
        unsigned u4 = t16[((size_t)c1.x << 6) + lane];
        unsigned u5 = t16[((size_t)c1.y << 6) + lane];
        unsigned u6 = t16[((size_t)c1.z << 6) + lane];
        unsigned u7 = t16[((size_t)c1.w << 6) + lane];
        unsigned u8 = t16[((size_t)c2.x << 6) + lane];
        unsigned u9 = t16[((size_t)c2.y << 6) + lane];
        unsigned ua = t16[((size_t)c2.z << 6) + lane];
        unsigned ub = t16[((size_t)c2.w << 6) + lane];
        unsigned uc = t16[((size_t)c3.x << 6) + lane];
        unsigned ud = t16[((size_t)c3.y << 6) + lane];
        unsigned ue = t16[((size_t)c3.z << 6) + lane];
        unsigned uf = t16[((size_t)c3.w << 6) + lane];
        acc += __uint_as_float(u0 << 16);
        acc += __uint_as_float(u1 << 16);
        acc += __uint_as_float(u2 << 16);
        acc += __uint_as_float(u3 << 16);
        acc += __uint_as_float(u4 << 16);
        acc += __uint_as_float(u5 << 16);
        acc += __uint_as_float(u6 << 16);
        acc += __uint_as_float(u7 << 16);
        acc += __uint_as_float(u8 << 16);
        acc += __uint_as_float(u9 << 16);
        acc += __uint_as_float(ua << 16);
        acc += __uint_as_float(ub << 16);
        acc += __uint_as_float(uc << 16);
        acc += __uint_as_float(ud << 16);
        acc += __uint_as_float(ue << 16);
        acc += __uint_as_float(uf << 16);
    }
    out[(size_t)w * 64 + lane] = (__bf16)fmaxf(dinv[w] * acc + bias[lane], 0.f);
}

// ---------------- fused mean-pool + MLP head ----------------
__global__ __launch_bounds__(256) void k_poolmlp(const unsigned short* __restrict__ h,
                                                 const int* __restrict__ gstart,
                                                 const float* __restrict__ demo,
                                                 const float* __restrict__ Wf1,
                                                 const float* __restrict__ bf1,
                                                 const float* __restrict__ Wf2,
                                                 const float* __restrict__ bf2,
                                                 const float* __restrict__ Wf3,
                                                 const float* __restrict__ bf3,
                                                 float* __restrict__ out, int G) {
    int g = blockIdx.x;
    int tid = threadIdx.x;
    int lane = tid & 63;
    int wv = tid >> 6;
    int s = gstart[g], e = gstart[g + 1];
    float acc = 0.f;
    for (int i = s + wv; i < e; i += 4)
        acc += __uint_as_float((unsigned)h[(size_t)i * 64 + lane] << 16);
    __shared__ float red[4][64];
    __shared__ float zin[72];
    __shared__ float z1[64];
    __shared__ float z2[32];
    red[wv][lane] = acc;
    if (tid >= 64 && tid < 72) zin[tid] = demo[g * 8 + (tid - 64)];
    __syncthreads();
    if (tid < 64) {
        float v = red[0][tid] + red[1][tid] + red[2][tid] + red[3][tid];
        zin[tid] = v / fmaxf((float)(e - s), 1.0f);
    }
    __syncthreads();
    if (tid < 64) {
        float a = bf1[tid];
        for (int k = 0; k < 72; k++) a += zin[k] * Wf1[k * 64 + tid];
        z1[tid] = fmaxf(a, 0.f);
    }
    __syncthreads();
    if (tid < 32) {
        float a2 = bf2[tid];
        for (int k = 0; k < 64; k++) a2 += z1[k] * Wf2[k * 32 + tid];
        z2[tid] = fmaxf(a2, 0.f);
    }
    __syncthreads();
    if (tid < 2) {
        float a3 = bf3[tid];
        for (int k = 0; k < 32; k++) a3 += z2[k] * Wf3[k * 2 + tid];
        out[g * 2 + tid] = a3;
    }
}

extern "C" void kernel_launch(void* const* d_in, const int* in_sizes, int n_in,
                              void* d_out, int out_size, void* d_ws, size_t ws_size,
                              hipStream_t stream) {
    const float* x    = (const float*)d_in[0];
    const int*   ei   = (const int*)d_in[1];
    const int*   batch= (const int*)d_in[2];
    const float* demo = (const float*)d_in[3];
    const float* W1   = (const float*)d_in[4];
    const float* b1   = (const float*)d_in[5];
    const float* W2   = (const float*)d_in[6];
    const float* b2   = (const float*)d_in[7];
    const float* W3   = (const float*)d_in[8];
    const float* b3   = (const float*)d_in[9];
    const float* Wf1  = (const float*)d_in[10];
    const float* bf1  = (const float*)d_in[11];
    const float* Wf2  = (const float*)d_in[12];
    const float* bf2  = (const float*)d_in[13];
    const float* Wf3  = (const float*)d_in[14];
    const float* bf3  = (const float*)d_in[15];
    float* out = (float*)d_out;

    const int n = in_sizes[0] / 128;  // 50000
    const int E = in_sizes[1] / 2;    // 600000
    const int G = in_sizes[3] / 8;    // 100
    const int Epad = E + 15 * n;      // worst-case padded CSR size (pad to 16)
    const int nchunks = (n + 4095) / 4096;       // scan chunks (13)
    const int EC = (E + ECHUNK - 1) / ECHUNK;    // edge chunks (147)
    const int nbuck = (n + 127) / 128;           // row buckets (391)

    char* ws = (char*)d_ws;
    auto alloc = [&](size_t bytes) {
        char* p = ws;
        ws += (bytes + 255) & ~(size_t)255;
        return p;
    };
    int*    cnt    = (int*)alloc((size_t)n * 4);
    float*  dinv   = (float*)alloc((size_t)n * 4);
    int*    rowptr = (int*)alloc((size_t)(n + 1) * 4);
    int*    fill2  = (int*)alloc((size_t)n * 4);
    int*    partial= (int*)alloc((size_t)nchunks * 4);
    int*    col    = (int*)alloc((size_t)Epad * 4);
    int2*   binbuf = (int2*)alloc((size_t)EC * nbuck * BCAP * 8);
    int*    bcnt   = (int*)alloc((size_t)EC * nbuck * 4);
    __bf16* tbf    = (__bf16*)alloc((size_t)(n + 1) * 128 * 2);  // ts (layers 1/2), row n = 0
    __bf16* hbuf   = (__bf16*)alloc((size_t)n * 128 * 2);        // agg out bf16
    __bf16* t3bf   = (__bf16*)alloc((size_t)(n + 1) * 64 * 2);   // ts layer 3, row n = 0
    __bf16* h3     = (__bf16*)alloc((size_t)n * 64 * 2);         // agg3 out (bf16)
    __bf16* Wp1h   = (__bf16*)alloc(128 * 128 * 2);
    __bf16* Wp1l   = (__bf16*)alloc(128 * 128 * 2);
    __bf16* Wp2h   = (__bf16*)alloc(128 * 128 * 2);
    __bf16* Wp2l   = (__bf16*)alloc(128 * 128 * 2);
    __bf16* Wp3h   = (__bf16*)alloc(128 * 64 * 2);
    __bf16* Wp3l   = (__bf16*)alloc(128 * 64 * 2);
    int*    gstart = (int*)alloc((size_t)(G + 1) * 4);

    const int* srcv = ei;
    const int* dstv = ei + E;

    hipMemsetAsync(cnt, 0, (size_t)n * 4, stream);

    const int EB = (E + 255) / 256;
    k_pre<<<EB + 21, 256, 0, stream>>>(dstv, cnt, batch, gstart, W1, Wp1h, Wp1l,
                                       W2, W3, Wp2h, Wp2l, Wp3h, Wp3l, E, n, G, EB);
    k_sum<<<nchunks, 1024, 0, stream>>>(cnt, partial, dinv,
                                        (unsigned int*)tbf, (unsigned int*)t3bf, n);
    k_out<<<nchunks, 1024, 0, stream>>>(cnt, partial, rowptr, fill2, n, nchunks);

    int waves = (n + 15) / 16;
    int gemm_blocks = (waves + 3) / 4;
    int gemm1_blocks = (waves + 15) / 16;  // 16 waves per 1024-thread block
    int agg_blocks = (int)(((size_t)n * 64 + 255) / 256);

    // phase 1: private-region binning || gemm1
    k_bin3<<<EC + gemm1_blocks, 1024, 0, stream>>>(srcv, dstv, binbuf, bcnt, E, EC, nbuck,
                                                   x, Wp1h, Wp1l, dinv, tbf, n);
    // phase 2: bucket -> staged CSR, coalesced writeout
    k_csr3<<<nbuck, 1024, 0, stream>>>(binbuf, bcnt, rowptr, fill2, col, n, EC, nbuck);

    // Layer 1 aggregation
    k_agg128<<<agg_blocks, 256, 0, stream>>>((const unsigned int*)tbf, rowptr, col,
                                             dinv, b1, (unsigned int*)hbuf, n);
    // Layer 2
    k_gemm_bf16<8><<<gemm_blocks, 256, 0, stream>>>(hbuf, Wp2h, Wp2l, dinv, tbf, n);
    k_agg128<<<agg_blocks, 256, 0, stream>>>((const unsigned int*)tbf, rowptr, col,
                                             dinv, b2, (unsigned int*)hbuf, n);
    // Layer 3 (128 -> 64)
    k_gemm_bf16<4><<<gemm_blocks, 256, 0, stream>>>(hbuf, Wp3h, Wp3l, dinv, t3bf, n);
    k_agg64<<<agg_blocks, 256, 0, stream>>>((const unsigned short*)t3bf, rowptr, col,
                                            dinv, b3, h3, n);

    k_poolmlp<<<G, 256, 0, stream>>>((const unsigned short*)h3, gstart, demo,
                                     Wf1, bf1, Wf2, bf2, Wf3, bf3, out, G);
}

// Round 16
// 264.888 us; speedup vs baseline: 1.1864x; 1.0923x over previous
//
#include <hip/hip_runtime.h>

// ---------------------------------------------------------------------------
// ROIAwareGCN: 3x GCNConv + mean-pool + MLP.
// R1..R14: see journal. Key survivors: MFMA split-bf16 GEMMs (dinv folded in
// epilogue), pure gather-sum agg over bf16 ts with zero-row padding, block-
// private edge binning + per-bucket staged coalesced CSR (R14: 314->289).
// R15: front-end restructure -- degree histogram (600k global atomics), cnt
// memset, k_sum and k_out all DELETED; per-row degrees recovered from the
// binning counts with the proven R14 per-bucket skeleton:
//   k_bin (binning + gstart + wpack) -> k_rows (deg/dinv/btot per bucket) ->
//   k_base (scan 391 totals) -> k_place (rowptr finalize + staged col
//   writeout + gemm1 tail) -> aggs/gemms unchanged. 10 dispatches.
// ---------------------------------------------------------------------------

typedef __bf16 bf16x8 __attribute__((ext_vector_type(8)));
typedef float f32x4 __attribute__((ext_vector_type(4)));

__device__ __forceinline__ float bflo(unsigned u) { return __uint_as_float(u << 16); }
__device__ __forceinline__ float bfhi(unsigned u) { return __uint_as_float(u & 0xffff0000u); }

union BF2 {
    __bf16 h[2];
    unsigned u;
};

#define PAD(c) (((c) + 15) & ~15)
#define BCAP 64
#define ECHUNK 4096

// ---------------- W pre-pack into MFMA B-fragment layout ----------------
__device__ __forceinline__ void wpack_block(const float* __restrict__ W,
                                            __bf16* __restrict__ hi,
                                            __bf16* __restrict__ lo, int N, int b, int l) {
    int t = b >> 2, c = b & 3;
    int k0 = c * 32 + (l >> 4) * 8;
    int ncol = t * 16 + (l & 15);
    size_t base = ((size_t)b * 64 + l) * 8;
#pragma unroll
    for (int j = 0; j < 8; j++) {
        float v = W[(size_t)(k0 + j) * N + ncol];
        __bf16 h = (__bf16)v;
        hi[base + j] = h;
        lo[base + j] = (__bf16)(v - (float)h);
    }
}

// ---- k_bin: block-private edge binning + gstart + wpack(W1,W2,W3) ----
__global__ __launch_bounds__(1024) void k_bin(const int* __restrict__ src,
                                              const int* __restrict__ dst,
                                              int2* __restrict__ binbuf,
                                              int* __restrict__ bcnt,
                                              const int* __restrict__ batch,
                                              int* __restrict__ gstart,
                                              const float* __restrict__ W1,
                                              const float* __restrict__ W2,
                                              const float* __restrict__ W3,
                                              __bf16* __restrict__ Wp1h, __bf16* __restrict__ Wp1l,
                                              __bf16* __restrict__ Wp2h, __bf16* __restrict__ Wp2l,
                                              __bf16* __restrict__ Wp3h, __bf16* __restrict__ Wp3l,
                                              int E, int EC, int nbuck, int n, int G) {
    int b = blockIdx.x;
    int tid = threadIdx.x;
    if (b < EC) {
        __shared__ int lcur[512];
        for (int i = tid; i < nbuck; i += 1024) lcur[i] = 0;
        __syncthreads();
        int e0 = b * ECHUNK;
        int cntE = E - e0;
        if (cntE > ECHUNK) cntE = ECHUNK;
#pragma unroll
        for (int k = 0; k < 4; k++) {
            int idx = tid + k * 1024;
            if (idx < cntE) {
                int s = src[e0 + idx];
                int d = dst[e0 + idx];
                int bk = d >> 7;
                int slot = atomicAdd(&lcur[bk], 1);
                if (slot < BCAP) {
                    int2 sd = {s, d};
                    binbuf[((size_t)b * nbuck + bk) * BCAP + slot] = sd;
                }
            }
        }
        __syncthreads();
        for (int bk = tid; bk < nbuck; bk += 1024) {
            int c = lcur[bk];
            bcnt[b * nbuck + bk] = (c < BCAP) ? c : BCAP;
        }
        return;
    }
    if (b == EC) {
        int g = tid;
        if (g <= G) {
            int lo = 0, hi = n;
            while (lo < hi) {
                int mid = (lo + hi) >> 1;
                if (batch[mid] < g) lo = mid + 1; else hi = mid;
            }
            gstart[g] = lo;
        }
        return;
    }
    int b64 = (b - EC - 1) * 16 + (tid >> 6);  // 0..79
    int l = tid & 63;
    if (b64 < 32) wpack_block(W1, Wp1h, Wp1l, 128, b64, l);
    else if (b64 < 64) wpack_block(W2, Wp2h, Wp2l, 128, b64 - 32, l);
    else if (b64 < 80) wpack_block(W3, Wp3h, Wp3l, 64, b64 - 64, l);
}

// ---- k_rows: per bucket, recover row degrees from binbuf; dinv, btot ----
__global__ __launch_bounds__(1024) void k_rows(const int2* __restrict__ binbuf,
                                               const int* __restrict__ bcnt,
                                               int* __restrict__ gdeg,
                                               float* __restrict__ dinv,
                                               int* __restrict__ btot,
                                               unsigned int* __restrict__ tz128,
                                               unsigned int* __restrict__ tz64,
                                               int n, int EC, int nbuck) {
    __shared__ int lcnt[160];
    __shared__ int lpre[161];
    __shared__ int deg[128];
    int b = blockIdx.x;
    int tid = threadIdx.x;
    int lane = tid & 63;
    int wid = tid >> 6;
    int r0 = b << 7;
    int r1 = r0 + 128;
    if (r1 > n) r1 = n;
    int nrows = r1 - r0;
    if (b == 0) {  // zero row n of the two gather targets
        if (tid < 64) tz128[(size_t)n * 64 + tid] = 0u;
        else if (tid < 96) tz64[(size_t)n * 32 + (tid - 64)] = 0u;
    }
    for (int c = tid; c < EC; c += 1024) lcnt[c] = bcnt[c * nbuck + b];
    if (tid < 128) deg[tid] = 0;
    __syncthreads();
    if (wid == 0) {
        int carry = 0;
        for (int bb = 0; bb < EC; bb += 64) {
            int idx = bb + lane;
            int val = (idx < EC) ? lcnt[idx] : 0;
            int sc = val;
#pragma unroll
            for (int d = 1; d < 64; d <<= 1) {
                int o = __shfl_up(sc, d);
                if (lane >= d) sc += o;
            }
            int grp = __shfl(sc, 63);
            if (idx < EC) lpre[idx] = sc - val + carry;
            carry += grp;
        }
        if (lane == 0) lpre[EC] = carry;
    }
    __syncthreads();
    int T = lpre[EC];
    for (int i = tid; i < T; i += 1024) {
        int lo = 0, hi = EC;
        while (lo < hi) {
            int mid = (lo + hi) >> 1;
            if (lpre[mid + 1] <= i) lo = mid + 1; else hi = mid;
        }
        int j = i - lpre[lo];
        int2 sd = binbuf[((size_t)lo * nbuck + b) * BCAP + j];
        unsigned r = (unsigned)(sd.y - r0);
        if (r < (unsigned)nrows) atomicAdd(&deg[r], 1);
    }
    __syncthreads();
    if (wid == 0) {  // sum padded degs (order-independent)
        int carry = 0;
#pragma unroll
        for (int bb = 0; bb < 128; bb += 64) {
            int idx = bb + lane;
            int val = (idx < nrows) ? PAD(deg[idx]) : 0;
#pragma unroll
            for (int d = 32; d > 0; d >>= 1) val += __shfl_xor(val, d);
            carry += val;
        }
        if (lane == 0) btot[b] = carry;
    }
    if (tid < nrows) {
        int d = deg[tid];
        gdeg[r0 + tid] = d;
        dinv[r0 + tid] = rsqrtf((float)(d + 1));
    }
}

// ---- k_base: scan bucket totals -> bbase, rowptr[n] ----
__global__ __launch_bounds__(64) void k_base(const int* __restrict__ btot,
                                             int* __restrict__ bbase,
                                             int* __restrict__ rowptr,
                                             int n, int nbuck) {
    int lane = threadIdx.x;
    int carry = 0;
    for (int bb = 0; bb < nbuck; bb += 64) {
        int idx = bb + lane;
        int val = (idx < nbuck) ? btot[idx] : 0;
        int sc = val;
#pragma unroll
        for (int d = 1; d < 64; d <<= 1) {
            int o = __shfl_up(sc, d);
            if (lane >= d) sc += o;
        }
        int grp = __shfl(sc, 63);
        if (idx < nbuck) bbase[idx] = sc - val + carry;
        carry += grp;
    }
    if (lane == 0) {
        bbase[nbuck] = carry;
        rowptr[n] = carry;
    }
}

// ---- k_place: finalize rowptr + staged coalesced col writeout + gemm1 tail ----
__global__ __launch_bounds__(1024) void k_place(const int2* __restrict__ binbuf,
                                                const int* __restrict__ bcnt,
                                                const int* __restrict__ gdeg,
                                                const int* __restrict__ bbase,
                                                int* __restrict__ rowptr,
                                                int* __restrict__ col,
                                                int n, int EC, int nbuck,
                                                const float* __restrict__ A,
                                                const __bf16* __restrict__ Wp_hi,
                                                const __bf16* __restrict__ Wp_lo,
                                                const float* __restrict__ dinv,
                                                __bf16* __restrict__ Cbf) {
    int b = blockIdx.x;
    int tid = threadIdx.x;
    if (b < nbuck) {
        __shared__ int cols_s[5120];
        __shared__ int lcnt[160];
        __shared__ int lpre[161];
        __shared__ int lloc[129];
        __shared__ int lfill[128];
        int lane = tid & 63;
        int wid = tid >> 6;
        int r0 = b << 7;
        int r1 = r0 + 128;
        if (r1 > n) r1 = n;
        int nrows = r1 - r0;
        int base = bbase[b];
        int size = bbase[b + 1] - base;
        for (int c = tid; c < EC; c += 1024) lcnt[c] = bcnt[c * nbuck + b];
        __syncthreads();
        if (wid == 0) {  // scan chunk counts
            int carry = 0;
            for (int bb = 0; bb < EC; bb += 64) {
                int idx = bb + lane;
                int val = (idx < EC) ? lcnt[idx] : 0;
                int sc = val;
#pragma unroll
                for (int d = 1; d < 64; d <<= 1) {
                    int o = __shfl_up(sc, d);
                    if (lane >= d) sc += o;
                }
                int grp = __shfl(sc, 63);
                if (idx < EC) lpre[idx] = sc - val + carry;
                carry += grp;
            }
            if (lane == 0) lpre[EC] = carry;
        } else if (wid == 1) {  // scan padded row degs -> local offsets
            int carry = 0;
#pragma unroll
            for (int bb = 0; bb < 128; bb += 64) {
                int idx = bb + lane;
                int val = (idx < nrows) ? PAD(gdeg[r0 + idx]) : 0;
                int sc = val;
#pragma unroll
                for (int d = 1; d < 64; d <<= 1) {
                    int o = __shfl_up(sc, d);
                    if (lane >= d) sc += o;
                }
                int grp = __shfl(sc, 63);
                lloc[idx] = sc - val + carry;
                carry += grp;
            }
            if (lane == 0) lloc[128] = carry;
        }
        __syncthreads();
        if (tid < nrows) {
            lfill[tid] = lloc[tid];
            rowptr[r0 + tid] = base + lloc[tid];
        }
        int T = lpre[EC];
        if (size <= 5120) {
            for (int i = tid; i < size; i += 1024) cols_s[i] = n;  // pads -> zero row
            __syncthreads();
            for (int i = tid; i < T; i += 1024) {
                int lo = 0, hi = EC;
                while (lo < hi) {
                    int mid = (lo + hi) >> 1;
                    if (lpre[mid + 1] <= i) lo = mid + 1; else hi = mid;
                }
                int j = i - lpre[lo];
                int2 sd = binbuf[((size_t)lo * nbuck + b) * BCAP + j];
                unsigned r = (unsigned)(sd.y - r0);
                if (r < (unsigned)nrows) {
                    int pos = atomicAdd(&lfill[r], 1);
                    if ((unsigned)pos < (unsigned)size) cols_s[pos] = sd.x;
                }
            }
            __syncthreads();
            for (int i = tid; i < size; i += 1024) col[base + i] = cols_s[i];
        } else {
            // fallback (statistically unreachable): bucket-local direct scatter
            __syncthreads();
            for (int i = tid; i < T; i += 1024) {
                int lo = 0, hi = EC;
                while (lo < hi) {
                    int mid = (lo + hi) >> 1;
                    if (lpre[mid + 1] <= i) lo = mid + 1; else hi = mid;
                }
                int j = i - lpre[lo];
                int2 sd = binbuf[((size_t)lo * nbuck + b) * BCAP + j];
                unsigned r = (unsigned)(sd.y - r0);
                if (r < (unsigned)nrows) {
                    int pos = atomicAdd(&lfill[r], 1);
                    if (pos < size) col[base + pos] = sd.x;
                }
            }
            __syncthreads();
            if (tid < nrows) {
                int pend = lloc[tid + 1];
                for (int p = lloc[tid] + gdeg[r0 + tid]; p < pend; p++) col[base + p] = n;
            }
        }
        return;
    }
    // ---- gemm1 tail: fp32 A, hi/lo split, 3 mfma per K-chunk; *dinv ----
    constexpr int NT = 8;
    constexpr int N = NT * 16;
    int bid = b - nbuck;
    int wave = bid * 16 + (tid >> 6);
    int lane = tid & 63;
    int row0 = wave * 16;
    if (row0 >= n) return;
    int m = lane & 15;
    int q = lane >> 4;
    int row = row0 + m;
    if (row >= n) row = n - 1;
    const float* ap = A + (size_t)row * 128 + q * 8;
    bf16x8 ahi[4], alo[4];
#pragma unroll
    for (int c = 0; c < 4; c++) {
        float4 v0 = *(const float4*)(ap + c * 32);
        float4 v1 = *(const float4*)(ap + c * 32 + 4);
        float vv[8] = {v0.x, v0.y, v0.z, v0.w, v1.x, v1.y, v1.z, v1.w};
#pragma unroll
        for (int j = 0; j < 8; j++) {
            __bf16 h = (__bf16)vv[j];
            ahi[c][j] = h;
            alo[c][j] = (__bf16)(vv[j] - (float)h);
        }
    }
    float dscale[4];
#pragma unroll
    for (int r = 0; r < 4; r++) {
        int rr = row0 + q * 4 + r;
        dscale[r] = dinv[rr < n ? rr : (n - 1)];
    }
#pragma unroll
    for (int t = 0; t < NT; t++) {
        f32x4 acc = {0.f, 0.f, 0.f, 0.f};
#pragma unroll
        for (int c = 0; c < 4; c++) {
            size_t off = ((size_t)(t * 4 + c) * 64 + lane) * 8;
            bf16x8 bh = *(const bf16x8*)(Wp_hi + off);
            bf16x8 bl = *(const bf16x8*)(Wp_lo + off);
            acc = __builtin_amdgcn_mfma_f32_16x16x32_bf16(ahi[c], bh, acc, 0, 0, 0);
            acc = __builtin_amdgcn_mfma_f32_16x16x32_bf16(alo[c], bh, acc, 0, 0, 0);
            acc = __builtin_amdgcn_mfma_f32_16x16x32_bf16(ahi[c], bl, acc, 0, 0, 0);
        }
        int colx = t * 16 + m;
#pragma unroll
        for (int r = 0; r < 4; r++) {
            int orow = row0 + q * 4 + r;
            if (orow < n) Cbf[(size_t)orow * N + colx] = (__bf16)(acc[r] * dscale[r]);
        }
    }
}

// ---------------- bf16-A MFMA GEMM (layers 2/3), epilogue *dinv ----------------
template <int NT>
__global__ __launch_bounds__(256) void k_gemm_bf16(const __bf16* __restrict__ A,
                                                   const __bf16* __restrict__ Wp_hi,
                                                   const __bf16* __restrict__ Wp_lo,
                                                   const float* __restrict__ dinv,
                                                   __bf16* __restrict__ Cbf, int n) {
    constexpr int N = NT * 16;
    int wave = (int)((blockIdx.x * 256u + threadIdx.x) >> 6);
    int lane = threadIdx.x & 63;
    int row0 = wave * 16;
    if (row0 >= n) return;
    int m = lane & 15;
    int q = lane >> 4;
    int row = row0 + m;
    if (row >= n) row = n - 1;
    const __bf16* ap = A + (size_t)row * 128 + q * 8;
    bf16x8 a[4];
#pragma unroll
    for (int c = 0; c < 4; c++) a[c] = *(const bf16x8*)(ap + c * 32);
    float dscale[4];
#pragma unroll
    for (int r = 0; r < 4; r++) {
        int rr = row0 + q * 4 + r;
        dscale[r] = dinv[rr < n ? rr : (n - 1)];
    }
#pragma unroll
    for (int t = 0; t < NT; t++) {
        f32x4 acc = {0.f, 0.f, 0.f, 0.f};
#pragma unroll
        for (int c = 0; c < 4; c++) {
            size_t off = ((size_t)(t * 4 + c) * 64 + lane) * 8;
            bf16x8 bh = *(const bf16x8*)(Wp_hi + off);
            bf16x8 bl = *(const bf16x8*)(Wp_lo + off);
            acc = __builtin_amdgcn_mfma_f32_16x16x32_bf16(a[c], bh, acc, 0, 0, 0);
            acc = __builtin_amdgcn_mfma_f32_16x16x32_bf16(a[c], bl, acc, 0, 0, 0);
        }
        int colx = t * 16 + m;
#pragma unroll
        for (int r = 0; r < 4; r++) {
            int orow = row0 + q * 4 + r;
            if (orow < n) Cbf[(size_t)orow * N + colx] = (__bf16)(acc[r] * dscale[r]);
        }
    }
}

// ---------------- aggregation: pure gather-sum; rows are k x 16 slots ----------------
__global__ __launch_bounds__(256) void k_agg128(const unsigned int* __restrict__ t32,
                                                const int* __restrict__ rowptr,
                                                const int* __restrict__ col,
                                                const float* __restrict__ dinv,
                                                const float* __restrict__ bias,
                                                unsigned int* __restrict__ out, int n) {
    int w = (int)((blockIdx.x * 256u + threadIdx.x) >> 6);
    int lane = threadIdx.x & 63;
    if (w >= n) return;
    unsigned us = t32[(size_t)w * 64 + lane];
    float a0 = bflo(us);
    float a1 = bfhi(us);
    int p = rowptr[w], pe = rowptr[w + 1];
    for (; p < pe; p += 16) {
        int4 c0 = *(const int4*)(col + p);
        int4 c1 = *(const int4*)(col + p + 4);
        int4 c2 = *(const int4*)(col + p + 8);
        int4 c3 = *(const int4*)(col + p + 12);
        unsigned u0 = t32[((size_t)c0.x << 6) + lane];
        unsigned u1 = t32[((size_t)c0.y << 6) + lane];
        unsigned u2 = t32[((size_t)c0.z << 6) + lane];
        unsigned u3 = t32[((size_t)c0.w << 6) + lane];
        unsigned u4 = t32[((size_t)c1.x << 6) + lane];
        unsigned u5 = t32[((size_t)c1.y << 6) + lane];
        unsigned u6 = t32[((size_t)c1.z << 6) + lane];
        unsigned u7 = t32[((size_t)c1.w << 6) + lane];
        unsigned u8 = t32[((size_t)c2.x << 6) + lane];
        unsigned u9 = t32[((size_t)c2.y << 6) + lane];
        unsigned ua = t32[((size_t)c2.z << 6) + lane];
        unsigned ub = t32[((size_t)c2.w << 6) + lane];
        unsigned uc = t32[((size_t)c3.x << 6) + lane];
        unsigned ud = t32[((size_t)c3.y << 6) + lane];
        unsigned ue = t32[((size_t)c3.z << 6) + lane];
        unsigned uf = t32[((size_t)c3.w << 6) + lane];
        a0 += bflo(u0); a1 += bfhi(u0);
        a0 += bflo(u1); a1 += bfhi(u1);
        a0 += bflo(u2); a1 += bfhi(u2);
        a0 += bflo(u3); a1 += bfhi(u3);
        a0 += bflo(u4); a1 += bfhi(u4);
        a0 += bflo(u5); a1 += bfhi(u5);
        a0 += bflo(u6); a1 += bfhi(u6);
        a0 += bflo(u7); a1 += bfhi(u7);
        a0 += bflo(u8); a1 += bfhi(u8);
        a0 += bflo(u9); a1 += bfhi(u9);
        a0 += bflo(ua); a1 += bfhi(ua);
        a0 += bflo(ub); a1 += bfhi(ub);
        a0 += bflo(uc); a1 += bfhi(uc);
        a0 += bflo(ud); a1 += bfhi(ud);
        a0 += bflo(ue); a1 += bfhi(ue);
        a0 += bflo(uf); a1 += bfhi(uf);
    }
    float di = dinv[w];
    BF2 o;
    o.h[0] = (__bf16)fmaxf(di * a0 + bias[lane * 2], 0.f);
    o.h[1] = (__bf16)fmaxf(di * a1 + bias[lane * 2 + 1], 0.f);
    out[(size_t)w * 64 + lane] = o.u;
}

__global__ __launch_bounds__(256) void k_agg64(const unsigned short* __restrict__ t16,
                                               const int* __restrict__ rowptr,
                                               const int* __restrict__ col,
                                               const float* __restrict__ dinv,
                                               const float* __restrict__ bias,
                                               __bf16* __restrict__ out, int n) {
    int w = (int)((blockIdx.x * 256u + threadIdx.x) >> 6);
    int lane = threadIdx.x & 63;
    if (w >= n) return;
    float acc = __uint_as_float((unsigned)t16[(size_t)w * 64 + lane] << 16);
    int p = rowptr[w], pe = rowptr[w + 1];
    for (; p < pe; p += 16) {
        int4 c0 = *(const int4*)(col + p);
        int4 c1 = *(const int4*)(col + p + 4);
        int4 c2 = *(const int4*)(col + p + 8);
        int4 c3 = *(const int4*)(col + p + 12);
        unsigned u0 = t16[((size_t)c0.x << 6) + lane];
        unsigned u1 = t16[((size_t)c0.y << 6) + lane];
        unsigned u2 = t16[((size_t)c0.z << 6) + lane];
        unsigned u3 = t16[((size_t)c0.w << 6) + lane];
        unsigned u4 = t16[((size_t)c1.x << 6) + lane];
        unsigned u5 = t16[((size_t)c1.y << 6) + lane];
        unsigned u6 = t16[((size_t)c1.z << 6) + lane];
        unsigned u7 = t16[((size_t)c1.w << 6) + lane];
        unsigned u8 = t16[((size_t)c2.x << 6) + lane];
        unsigned u9 = t16[((size_t)c2.y << 6) + lane];
        unsigned ua = t16[((size_t)c2.z << 6) + lane];
        unsigned ub = t16[((size_t)c2.w << 6) + lane];
        unsigned uc = t16[((size_t)c3.x << 6) + lane];
        unsigned ud = t16[((size_t)c3.y << 6) + lane];
        unsigned ue = t16[((size_t)c3.z << 6) + lane];
        unsigned uf = t16[((size_t)c3.w << 6) + lane];
        acc += __uint_as_float(u0 << 16);
        acc += __uint_as_float(u1 << 16);
        acc += __uint_as_float(u2 << 16);
        acc += __uint_as_float(u3 << 16);
        acc += __uint_as_float(u4 << 16);
        acc += __uint_as_float(u5 << 16);
        acc += __uint_as_float(u6 << 16);
        acc += __uint_as_float(u7 << 16);
        acc += __uint_as_float(u8 << 16);
        acc += __uint_as_float(u9 << 16);
        acc += __uint_as_float(ua << 16);
        acc += __uint_as_float(ub << 16);
        acc += __uint_as_float(uc << 16);
        acc += __uint_as_float(ud << 16);
        acc += __uint_as_float(ue << 16);
        acc += __uint_as_float(uf << 16);
    }
    out[(size_t)w * 64 + lane] = (__bf16)fmaxf(dinv[w] * acc + bias[lane], 0.f);
}

// ---------------- fused mean-pool + MLP head ----------------
__global__ __launch_bounds__(256) void k_poolmlp(const unsigned short* __restrict__ h,
                                                 const int* __restrict__ gstart,
                                                 const float* __restrict__ demo,
                                                 const float* __restrict__ Wf1,
                                                 const float* __restrict__ bf1,
                                                 const float* __restrict__ Wf2,
                                                 const float* __restrict__ bf2,
                                                 const float* __restrict__ Wf3,
                                                 const float* __restrict__ bf3,
                                                 float* __restrict__ out, int G) {
    int g = blockIdx.x;
    int tid = threadIdx.x;
    int lane = tid & 63;
    int wv = tid >> 6;
    int s = gstart[g], e = gstart[g + 1];
    float acc = 0.f;
    for (int i = s + wv; i < e; i += 4)
        acc += __uint_as_float((unsigned)h[(size_t)i * 64 + lane] << 16);
    __shared__ float red[4][64];
    __shared__ float zin[72];
    __shared__ float z1[64];
    __shared__ float z2[32];
    red[wv][lane] = acc;
    if (tid >= 64 && tid < 72) zin[tid] = demo[g * 8 + (tid - 64)];
    __syncthreads();
    if (tid < 64) {
        float v = red[0][tid] + red[1][tid] + red[2][tid] + red[3][tid];
        zin[tid] = v / fmaxf((float)(e - s), 1.0f);
    }
    __syncthreads();
    if (tid < 64) {
        float a = bf1[tid];
        for (int k = 0; k < 72; k++) a += zin[k] * Wf1[k * 64 + tid];
        z1[tid] = fmaxf(a, 0.f);
    }
    __syncthreads();
    if (tid < 32) {
        float a2 = bf2[tid];
        for (int k = 0; k < 64; k++) a2 += z1[k] * Wf2[k * 32 + tid];
        z2[tid] = fmaxf(a2, 0.f);
    }
    __syncthreads();
    if (tid < 2) {
        float a3 = bf3[tid];
        for (int k = 0; k < 32; k++) a3 += z2[k] * Wf3[k * 2 + tid];
        out[g * 2 + tid] = a3;
    }
}

extern "C" void kernel_launch(void* const* d_in, const int* in_sizes, int n_in,
                              void* d_out, int out_size, void* d_ws, size_t ws_size,
                              hipStream_t stream) {
    const float* x    = (const float*)d_in[0];
    const int*   ei   = (const int*)d_in[1];
    const int*   batch= (const int*)d_in[2];
    const float* demo = (const float*)d_in[3];
    const float* W1   = (const float*)d_in[4];
    const float* b1   = (const float*)d_in[5];
    const float* W2   = (const float*)d_in[6];
    const float* b2   = (const float*)d_in[7];
    const float* W3   = (const float*)d_in[8];
    const float* b3   = (const float*)d_in[9];
    const float* Wf1  = (const float*)d_in[10];
    const float* bf1  = (const float*)d_in[11];
    const float* Wf2  = (const float*)d_in[12];
    const float* bf2  = (const float*)d_in[13];
    const float* Wf3  = (const float*)d_in[14];
    const float* bf3  = (const float*)d_in[15];
    float* out = (float*)d_out;

    const int n = in_sizes[0] / 128;  // 50000
    const int E = in_sizes[1] / 2;    // 600000
    const int G = in_sizes[3] / 8;    // 100
    const int Epad = E + 15 * n;      // worst-case padded CSR size (pad to 16)
    const int EC = (E + ECHUNK - 1) / ECHUNK;    // edge chunks (147)
    const int nbuck = (n + 127) / 128;           // row buckets (391)

    char* ws = (char*)d_ws;
    auto alloc = [&](size_t bytes) {
        char* p = ws;
        ws += (bytes + 255) & ~(size_t)255;
        return p;
    };
    float*  dinv   = (float*)alloc((size_t)n * 4);
    int*    rowptr = (int*)alloc((size_t)(n + 1) * 4);
    int*    gdeg   = (int*)alloc((size_t)n * 4);
    int*    btot   = (int*)alloc((size_t)nbuck * 4);
    int*    bbase  = (int*)alloc((size_t)(nbuck + 1) * 4);
    int*    col    = (int*)alloc((size_t)Epad * 4);
    int2*   binbuf = (int2*)alloc((size_t)EC * nbuck * BCAP * 8);
    int*    bcnt   = (int*)alloc((size_t)EC * nbuck * 4);
    __bf16* tbf    = (__bf16*)alloc((size_t)(n + 1) * 128 * 2);  // ts (layers 1/2), row n = 0
    __bf16* hbuf   = (__bf16*)alloc((size_t)n * 128 * 2);        // agg out bf16
    __bf16* t3bf   = (__bf16*)alloc((size_t)(n + 1) * 64 * 2);   // ts layer 3, row n = 0
    __bf16* h3     = (__bf16*)alloc((size_t)n * 64 * 2);         // agg3 out (bf16)
    __bf16* Wp1h   = (__bf16*)alloc(128 * 128 * 2);
    __bf16* Wp1l   = (__bf16*)alloc(128 * 128 * 2);
    __bf16* Wp2h   = (__bf16*)alloc(128 * 128 * 2);
    __bf16* Wp2l   = (__bf16*)alloc(128 * 128 * 2);
    __bf16* Wp3h   = (__bf16*)alloc(128 * 64 * 2);
    __bf16* Wp3l   = (__bf16*)alloc(128 * 64 * 2);
    int*    gstart = (int*)alloc((size_t)(G + 1) * 4);

    const int* srcv = ei;
    const int* dstv = ei + E;

    int waves = (n + 15) / 16;
    int gemm_blocks = (waves + 3) / 4;
    int gemm1_blocks = (waves + 15) / 16;  // 16 waves per 1024-thread block
    int agg_blocks = (int)(((size_t)n * 64 + 255) / 256);

    // binning + gstart + wpack (no degree histogram, no memset)
    k_bin<<<EC + 1 + 5, 1024, 0, stream>>>(srcv, dstv, binbuf, bcnt, batch, gstart,
                                           W1, W2, W3, Wp1h, Wp1l, Wp2h, Wp2l,
                                           Wp3h, Wp3l, E, EC, nbuck, n, G);
    // per-bucket row degrees -> gdeg, dinv, btot (+ zero row n of ts buffers)
    k_rows<<<nbuck, 1024, 0, stream>>>(binbuf, bcnt, gdeg, dinv, btot,
                                       (unsigned int*)tbf, (unsigned int*)t3bf,
                                       n, EC, nbuck);
    // scan bucket totals
    k_base<<<1, 64, 0, stream>>>(btot, bbase, rowptr, n, nbuck);
    // finalize rowptr + staged coalesced col writeout || gemm1
    k_place<<<nbuck + gemm1_blocks, 1024, 0, stream>>>(binbuf, bcnt, gdeg, bbase,
                                                       rowptr, col, n, EC, nbuck,
                                                       x, Wp1h, Wp1l, dinv, tbf);

    // Layer 1 aggregation
    k_agg128<<<agg_blocks, 256, 0, stream>>>((const unsigned int*)tbf, rowptr, col,
                                             dinv, b1, (unsigned int*)hbuf, n);
    // Layer 2
    k_gemm_bf16<8><<<gemm_blocks, 256, 0, stream>>>(hbuf, Wp2h, Wp2l, dinv, tbf, n);
    k_agg128<<<agg_blocks, 256, 0, stream>>>((const unsigned int*)tbf, rowptr, col,
                                             dinv, b2, (unsigned int*)hbuf, n);
    // Layer 3 (128 -> 64)
    k_gemm_bf16<4><<<gemm_blocks, 256, 0, stream>>>(hbuf, Wp3h, Wp3l, dinv, t3bf, n);
    k_agg64<<<agg_blocks, 256, 0, stream>>>((const unsigned short*)t3bf, rowptr, col,
                                            dinv, b3, h3, n);

    k_poolmlp<<<G, 256, 0, stream>>>((const unsigned short*)h3, gstart, demo,
                                     Wf1, bf1, Wf2, bf2, Wf3, bf3, out, G);
}

// Round 18
// 254.471 us; speedup vs baseline: 1.2350x; 1.0409x over previous
//
#include <hip/hip_runtime.h>

// ---------------------------------------------------------------------------
// ROIAwareGCN: 3x GCNConv + mean-pool + MLP.
// R1..R15: see journal. Survivors: MFMA split-bf16 GEMMs (dinv in epilogue),
// pure gather-sum agg with zero-row-16 padding, block-private binning +
// per-bucket staged coalesced CSR, binning-derived degrees (289->265).
// R16/R17: ts (gather operand) stored fp8 e4m3 (OCP, HW cvt). R16 failed to
// compile: cvt_pk_f32_fp8 returns a gcc-vector; member .x on the call expr is
// illegal. R17 routes all conversions through an f32x2 helper. Halves agg
// gather traffic (dominant remaining cost). Accumulation fp32; hbuf/h3 bf16.
// ---------------------------------------------------------------------------

typedef __bf16 bf16x8 __attribute__((ext_vector_type(8)));
typedef float f32x4 __attribute__((ext_vector_type(4)));
typedef float f32x2 __attribute__((ext_vector_type(2)));

__device__ __forceinline__ unsigned char f32_to_fp8(float v) {
    return (unsigned char)(__builtin_amdgcn_cvt_pk_fp8_f32(v, 0.f, 0, false) & 0xff);
}
__device__ __forceinline__ f32x2 fp8x2_to_f32(unsigned u) {
    f32x2 r = __builtin_amdgcn_cvt_pk_f32_fp8(u, false);
    return r;
}
__device__ __forceinline__ float fp8_to_f32(unsigned u) {
    f32x2 r = __builtin_amdgcn_cvt_pk_f32_fp8(u, false);
    return r.x;
}

union BF2 {
    __bf16 h[2];
    unsigned u;
};

#define PAD(c) (((c) + 15) & ~15)
#define BCAP 64
#define ECHUNK 4096

// ---------------- W pre-pack into MFMA B-fragment layout ----------------
__device__ __forceinline__ void wpack_block(const float* __restrict__ W,
                                            __bf16* __restrict__ hi,
                                            __bf16* __restrict__ lo, int N, int b, int l) {
    int t = b >> 2, c = b & 3;
    int k0 = c * 32 + (l >> 4) * 8;
    int ncol = t * 16 + (l & 15);
    size_t base = ((size_t)b * 64 + l) * 8;
#pragma unroll
    for (int j = 0; j < 8; j++) {
        float v = W[(size_t)(k0 + j) * N + ncol];
        __bf16 h = (__bf16)v;
        hi[base + j] = h;
        lo[base + j] = (__bf16)(v - (float)h);
    }
}

// ---- k_bin: block-private edge binning + gstart + wpack(W1,W2,W3) ----
__global__ __launch_bounds__(1024) void k_bin(const int* __restrict__ src,
                                              const int* __restrict__ dst,
                                              int2* __restrict__ binbuf,
                                              int* __restrict__ bcnt,
                                              const int* __restrict__ batch,
                                              int* __restrict__ gstart,
                                              const float* __restrict__ W1,
                                              const float* __restrict__ W2,
                                              const float* __restrict__ W3,
                                              __bf16* __restrict__ Wp1h, __bf16* __restrict__ Wp1l,
                                              __bf16* __restrict__ Wp2h, __bf16* __restrict__ Wp2l,
                                              __bf16* __restrict__ Wp3h, __bf16* __restrict__ Wp3l,
                                              int E, int EC, int nbuck, int n, int G) {
    int b = blockIdx.x;
    int tid = threadIdx.x;
    if (b < EC) {
        __shared__ int lcur[512];
        for (int i = tid; i < nbuck; i += 1024) lcur[i] = 0;
        __syncthreads();
        int e0 = b * ECHUNK;
        int cntE = E - e0;
        if (cntE > ECHUNK) cntE = ECHUNK;
#pragma unroll
        for (int k = 0; k < 4; k++) {
            int idx = tid + k * 1024;
            if (idx < cntE) {
                int s = src[e0 + idx];
                int d = dst[e0 + idx];
                int bk = d >> 7;
                int slot = atomicAdd(&lcur[bk], 1);
                if (slot < BCAP) {
                    int2 sd = {s, d};
                    binbuf[((size_t)b * nbuck + bk) * BCAP + slot] = sd;
                }
            }
        }
        __syncthreads();
        for (int bk = tid; bk < nbuck; bk += 1024) {
            int c = lcur[bk];
            bcnt[b * nbuck + bk] = (c < BCAP) ? c : BCAP;
        }
        return;
    }
    if (b == EC) {
        int g = tid;
        if (g <= G) {
            int lo = 0, hi = n;
            while (lo < hi) {
                int mid = (lo + hi) >> 1;
                if (batch[mid] < g) lo = mid + 1; else hi = mid;
            }
            gstart[g] = lo;
        }
        return;
    }
    int b64 = (b - EC - 1) * 16 + (tid >> 6);  // 0..79
    int l = tid & 63;
    if (b64 < 32) wpack_block(W1, Wp1h, Wp1l, 128, b64, l);
    else if (b64 < 64) wpack_block(W2, Wp2h, Wp2l, 128, b64 - 32, l);
    else if (b64 < 80) wpack_block(W3, Wp3h, Wp3l, 64, b64 - 64, l);
}

// ---- k_rows: per bucket, recover row degrees from binbuf; dinv, btot ----
__global__ __launch_bounds__(1024) void k_rows(const int2* __restrict__ binbuf,
                                               const int* __restrict__ bcnt,
                                               int* __restrict__ gdeg,
                                               float* __restrict__ dinv,
                                               int* __restrict__ btot,
                                               unsigned int* __restrict__ tz128,
                                               unsigned int* __restrict__ tz64,
                                               int n, int EC, int nbuck) {
    __shared__ int lcnt[160];
    __shared__ int lpre[161];
    __shared__ int deg[128];
    int b = blockIdx.x;
    int tid = threadIdx.x;
    int lane = tid & 63;
    int wid = tid >> 6;
    int r0 = b << 7;
    int r1 = r0 + 128;
    if (r1 > n) r1 = n;
    int nrows = r1 - r0;
    if (b == 0) {  // zero row n of the two fp8 gather targets (128 B + 64 B)
        if (tid < 32) tz128[(size_t)n * 32 + tid] = 0u;
        else if (tid < 48) tz64[(size_t)n * 16 + (tid - 32)] = 0u;
    }
    for (int c = tid; c < EC; c += 1024) lcnt[c] = bcnt[c * nbuck + b];
    if (tid < 128) deg[tid] = 0;
    __syncthreads();
    if (wid == 0) {
        int carry = 0;
        for (int bb = 0; bb < EC; bb += 64) {
            int idx = bb + lane;
            int val = (idx < EC) ? lcnt[idx] : 0;
            int sc = val;
#pragma unroll
            for (int d = 1; d < 64; d <<= 1) {
                int o = __shfl_up(sc, d);
                if (lane >= d) sc += o;
            }
            int grp = __shfl(sc, 63);
            if (idx < EC) lpre[idx] = sc - val + carry;
            carry += grp;
        }
        if (lane == 0) lpre[EC] = carry;
    }
    __syncthreads();
    int T = lpre[EC];
    for (int i = tid; i < T; i += 1024) {
        int lo = 0, hi = EC;
        while (lo < hi) {
            int mid = (lo + hi) >> 1;
            if (lpre[mid + 1] <= i) lo = mid + 1; else hi = mid;
        }
        int j = i - lpre[lo];
        int2 sd = binbuf[((size_t)lo * nbuck + b) * BCAP + j];
        unsigned r = (unsigned)(sd.y - r0);
        if (r < (unsigned)nrows) atomicAdd(&deg[r], 1);
    }
    __syncthreads();
    if (wid == 0) {  // sum padded degs (order-independent)
        int carry = 0;
#pragma unroll
        for (int bb = 0; bb < 128; bb += 64) {
            int idx = bb + lane;
            int val = (idx < nrows) ? PAD(deg[idx]) : 0;
#pragma unroll
            for (int d = 32; d > 0; d >>= 1) val += __shfl_xor(val, d);
            carry += val;
        }
        if (lane == 0) btot[b] = carry;
    }
    if (tid < nrows) {
        int d = deg[tid];
        gdeg[r0 + tid] = d;
        dinv[r0 + tid] = rsqrtf((float)(d + 1));
    }
}

// ---- k_base: scan bucket totals -> bbase, rowptr[n] ----
__global__ __launch_bounds__(64) void k_base(const int* __restrict__ btot,
                                             int* __restrict__ bbase,
                                             int* __restrict__ rowptr,
                                             int n, int nbuck) {
    int lane = threadIdx.x;
    int carry = 0;
    for (int bb = 0; bb < nbuck; bb += 64) {
        int idx = bb + lane;
        int val = (idx < nbuck) ? btot[idx] : 0;
        int sc = val;
#pragma unroll
        for (int d = 1; d < 64; d <<= 1) {
            int o = __shfl_up(sc, d);
            if (lane >= d) sc += o;
        }
        int grp = __shfl(sc, 63);
        if (idx < nbuck) bbase[idx] = sc - val + carry;
        carry += grp;
    }
    if (lane == 0) {
        bbase[nbuck] = carry;
        rowptr[n] = carry;
    }
}

// ---- k_place: finalize rowptr + staged coalesced col writeout + gemm1 tail ----
__global__ __launch_bounds__(1024) void k_place(const int2* __restrict__ binbuf,
                                                const int* __restrict__ bcnt,
                                                const int* __restrict__ gdeg,
                                                const int* __restrict__ bbase,
                                                int* __restrict__ rowptr,
                                                int* __restrict__ col,
                                                int n, int EC, int nbuck,
                                                const float* __restrict__ A,
                                                const __bf16* __restrict__ Wp_hi,
                                                const __bf16* __restrict__ Wp_lo,
                                                const float* __restrict__ dinv,
                                                unsigned char* __restrict__ Cf8) {
    int b = blockIdx.x;
    int tid = threadIdx.x;
    if (b < nbuck) {
        __shared__ int cols_s[5120];
        __shared__ int lcnt[160];
        __shared__ int lpre[161];
        __shared__ int lloc[129];
        __shared__ int lfill[128];
        int lane = tid & 63;
        int wid = tid >> 6;
        int r0 = b << 7;
        int r1 = r0 + 128;
        if (r1 > n) r1 = n;
        int nrows = r1 - r0;
        int base = bbase[b];
        int size = bbase[b + 1] - base;
        for (int c = tid; c < EC; c += 1024) lcnt[c] = bcnt[c * nbuck + b];
        __syncthreads();
        if (wid == 0) {  // scan chunk counts
            int carry = 0;
            for (int bb = 0; bb < EC; bb += 64) {
                int idx = bb + lane;
                int val = (idx < EC) ? lcnt[idx] : 0;
                int sc = val;
#pragma unroll
                for (int d = 1; d < 64; d <<= 1) {
                    int o = __shfl_up(sc, d);
                    if (lane >= d) sc += o;
                }
                int grp = __shfl(sc, 63);
                if (idx < EC) lpre[idx] = sc - val + carry;
                carry += grp;
            }
            if (lane == 0) lpre[EC] = carry;
        } else if (wid == 1) {  // scan padded row degs -> local offsets
            int carry = 0;
#pragma unroll
            for (int bb = 0; bb < 128; bb += 64) {
                int idx = bb + lane;
                int val = (idx < nrows) ? PAD(gdeg[r0 + idx]) : 0;
                int sc = val;
#pragma unroll
                for (int d = 1; d < 64; d <<= 1) {
                    int o = __shfl_up(sc, d);
                    if (lane >= d) sc += o;
                }
                int grp = __shfl(sc, 63);
                lloc[idx] = sc - val + carry;
                carry += grp;
            }
            if (lane == 0) lloc[128] = carry;
        }
        __syncthreads();
        if (tid < nrows) {
            lfill[tid] = lloc[tid];
            rowptr[r0 + tid] = base + lloc[tid];
        }
        int T = lpre[EC];
        if (size <= 5120) {
            for (int i = tid; i < size; i += 1024) cols_s[i] = n;  // pads -> zero row
            __syncthreads();
            for (int i = tid; i < T; i += 1024) {
                int lo = 0, hi = EC;
                while (lo < hi) {
                    int mid = (lo + hi) >> 1;
                    if (lpre[mid + 1] <= i) lo = mid + 1; else hi = mid;
                }
                int j = i - lpre[lo];
                int2 sd = binbuf[((size_t)lo * nbuck + b) * BCAP + j];
                unsigned r = (unsigned)(sd.y - r0);
                if (r < (unsigned)nrows) {
                    int pos = atomicAdd(&lfill[r], 1);
                    if ((unsigned)pos < (unsigned)size) cols_s[pos] = sd.x;
                }
            }
            __syncthreads();
            for (int i = tid; i < size; i += 1024) col[base + i] = cols_s[i];
        } else {
            // fallback (statistically unreachable): bucket-local direct scatter
            __syncthreads();
            for (int i = tid; i < T; i += 1024) {
                int lo = 0, hi = EC;
                while (lo < hi) {
                    int mid = (lo + hi) >> 1;
                    if (lpre[mid + 1] <= i) lo = mid + 1; else hi = mid;
                }
                int j = i - lpre[lo];
                int2 sd = binbuf[((size_t)lo * nbuck + b) * BCAP + j];
                unsigned r = (unsigned)(sd.y - r0);
                if (r < (unsigned)nrows) {
                    int pos = atomicAdd(&lfill[r], 1);
                    if (pos < size) col[base + pos] = sd.x;
                }
            }
            __syncthreads();
            if (tid < nrows) {
                int pend = lloc[tid + 1];
                for (int p = lloc[tid] + gdeg[r0 + tid]; p < pend; p++) col[base + p] = n;
            }
        }
        return;
    }
    // ---- gemm1 tail: fp32 A, hi/lo split, 3 mfma per K-chunk; *dinv; fp8 out ----
    constexpr int NT = 8;
    constexpr int N = NT * 16;
    int bid = b - nbuck;
    int wave = bid * 16 + (tid >> 6);
    int lane = tid & 63;
    int row0 = wave * 16;
    if (row0 >= n) return;
    int m = lane & 15;
    int q = lane >> 4;
    int row = row0 + m;
    if (row >= n) row = n - 1;
    const float* ap = A + (size_t)row * 128 + q * 8;
    bf16x8 ahi[4], alo[4];
#pragma unroll
    for (int c = 0; c < 4; c++) {
        float4 v0 = *(const float4*)(ap + c * 32);
        float4 v1 = *(const float4*)(ap + c * 32 + 4);
        float vv[8] = {v0.x, v0.y, v0.z, v0.w, v1.x, v1.y, v1.z, v1.w};
#pragma unroll
        for (int j = 0; j < 8; j++) {
            __bf16 h = (__bf16)vv[j];
            ahi[c][j] = h;
            alo[c][j] = (__bf16)(vv[j] - (float)h);
        }
    }
    float dscale[4];
#pragma unroll
    for (int r = 0; r < 4; r++) {
        int rr = row0 + q * 4 + r;
        dscale[r] = dinv[rr < n ? rr : (n - 1)];
    }
#pragma unroll
    for (int t = 0; t < NT; t++) {
        f32x4 acc = {0.f, 0.f, 0.f, 0.f};
#pragma unroll
        for (int c = 0; c < 4; c++) {
            size_t off = ((size_t)(t * 4 + c) * 64 + lane) * 8;
            bf16x8 bh = *(const bf16x8*)(Wp_hi + off);
            bf16x8 bl = *(const bf16x8*)(Wp_lo + off);
            acc = __builtin_amdgcn_mfma_f32_16x16x32_bf16(ahi[c], bh, acc, 0, 0, 0);
            acc = __builtin_amdgcn_mfma_f32_16x16x32_bf16(alo[c], bh, acc, 0, 0, 0);
            acc = __builtin_amdgcn_mfma_f32_16x16x32_bf16(ahi[c], bl, acc, 0, 0, 0);
        }
        int colx = t * 16 + m;
#pragma unroll
        for (int r = 0; r < 4; r++) {
            int orow = row0 + q * 4 + r;
            if (orow < n) Cf8[(size_t)orow * N + colx] = f32_to_fp8(acc[r] * dscale[r]);
        }
    }
}

// ---------------- bf16-A MFMA GEMM (layers 2/3), epilogue *dinv, fp8 out ----------------
template <int NT>
__global__ __launch_bounds__(256) void k_gemm_bf16(const __bf16* __restrict__ A,
                                                   const __bf16* __restrict__ Wp_hi,
                                                   const __bf16* __restrict__ Wp_lo,
                                                   const float* __restrict__ dinv,
                                                   unsigned char* __restrict__ Cf8, int n) {
    constexpr int N = NT * 16;
    int wave = (int)((blockIdx.x * 256u + threadIdx.x) >> 6);
    int lane = threadIdx.x & 63;
    int row0 = wave * 16;
    if (row0 >= n) return;
    int m = lane & 15;
    int q = lane >> 4;
    int row = row0 + m;
    if (row >= n) row = n - 1;
    const __bf16* ap = A + (size_t)row * 128 + q * 8;
    bf16x8 a[4];
#pragma unroll
    for (int c = 0; c < 4; c++) a[c] = *(const bf16x8*)(ap + c * 32);
    float dscale[4];
#pragma unroll
    for (int r = 0; r < 4; r++) {
        int rr = row0 + q * 4 + r;
        dscale[r] = dinv[rr < n ? rr : (n - 1)];
    }
#pragma unroll
    for (int t = 0; t < NT; t++) {
        f32x4 acc = {0.f, 0.f, 0.f, 0.f};
#pragma unroll
        for (int c = 0; c < 4; c++) {
            size_t off = ((size_t)(t * 4 + c) * 64 + lane) * 8;
            bf16x8 bh = *(const bf16x8*)(Wp_hi + off);
            bf16x8 bl = *(const bf16x8*)(Wp_lo + off);
            acc = __builtin_amdgcn_mfma_f32_16x16x32_bf16(a[c], bh, acc, 0, 0, 0);
            acc = __builtin_amdgcn_mfma_f32_16x16x32_bf16(a[c], bl, acc, 0, 0, 0);
        }
        int colx = t * 16 + m;
#pragma unroll
        for (int r = 0; r < 4; r++) {
            int orow = row0 + q * 4 + r;
            if (orow < n) Cf8[(size_t)orow * N + colx] = f32_to_fp8(acc[r] * dscale[r]);
        }
    }
}

// ---------------- aggregation: gather-sum over fp8 ts; rows k x 16 slots ----------------
__global__ __launch_bounds__(256) void k_agg128(const unsigned short* __restrict__ t8,
                                                const int* __restrict__ rowptr,
                                                const int* __restrict__ col,
                                                const float* __restrict__ dinv,
                                                const float* __restrict__ bias,
                                                unsigned int* __restrict__ out, int n) {
    int w = (int)((blockIdx.x * 256u + threadIdx.x) >> 6);
    int lane = threadIdx.x & 63;
    if (w >= n) return;
    f32x2 vs = fp8x2_to_f32((unsigned)t8[(size_t)w * 64 + lane]);
    float a0 = vs.x;
    float a1 = vs.y;
    int p = rowptr[w], pe = rowptr[w + 1];
    for (; p < pe; p += 16) {
        int4 c0 = *(const int4*)(col + p);
        int4 c1 = *(const int4*)(col + p + 4);
        int4 c2 = *(const int4*)(col + p + 8);
        int4 c3 = *(const int4*)(col + p + 12);
        unsigned u0 = t8[((size_t)c0.x << 6) + lane];
        unsigned u1 = t8[((size_t)c0.y << 6) + lane];
        unsigned u2 = t8[((size_t)c0.z << 6) + lane];
        unsigned u3 = t8[((size_t)c0.w << 6) + lane];
        unsigned u4 = t8[((size_t)c1.x << 6) + lane];
        unsigned u5 = t8[((size_t)c1.y << 6) + lane];
        unsigned u6 = t8[((size_t)c1.z << 6) + lane];
        unsigned u7 = t8[((size_t)c1.w << 6) + lane];
        unsigned u8 = t8[((size_t)c2.x << 6) + lane];
        unsigned u9 = t8[((size_t)c2.y << 6) + lane];
        unsigned ua = t8[((size_t)c2.z << 6) + lane];
        unsigned ub = t8[((size_t)c2.w << 6) + lane];
        unsigned uc = t8[((size_t)c3.x << 6) + lane];
        unsigned ud = t8[((size_t)c3.y << 6) + lane];
        unsigned ue = t8[((size_t)c3.z << 6) + lane];
        unsigned uf = t8[((size_t)c3.w << 6) + lane];
        f32x2 v;
        v = fp8x2_to_f32(u0); a0 += v.x; a1 += v.y;
        v = fp8x2_to_f32(u1); a0 += v.x; a1 += v.y;
        v = fp8x2_to_f32(u2); a0 += v.x; a1 += v.y;
        v = fp8x2_to_f32(u3); a0 += v.x; a1 += v.y;
        v = fp8x2_to_f32(u4); a0 += v.x; a1 += v.y;
        v = fp8x2_to_f32(u5); a0 += v.x; a1 += v.y;
        v = fp8x2_to_f32(u6); a0 += v.x; a1 += v.y;
        v = fp8x2_to_f32(u7); a0 += v.x; a1 += v.y;
        v = fp8x2_to_f32(u8); a0 += v.x; a1 += v.y;
        v = fp8x2_to_f32(u9); a0 += v.x; a1 += v.y;
        v = fp8x2_to_f32(ua); a0 += v.x; a1 += v.y;
        v = fp8x2_to_f32(ub); a0 += v.x; a1 += v.y;
        v = fp8x2_to_f32(uc); a0 += v.x; a1 += v.y;
        v = fp8x2_to_f32(ud); a0 += v.x; a1 += v.y;
        v = fp8x2_to_f32(ue); a0 += v.x; a1 += v.y;
        v = fp8x2_to_f32(uf); a0 += v.x; a1 += v.y;
    }
    float di = dinv[w];
    BF2 o;
    o.h[0] = (__bf16)fmaxf(di * a0 + bias[lane * 2], 0.f);
    o.h[1] = (__bf16)fmaxf(di * a1 + bias[lane * 2 + 1], 0.f);
    out[(size_t)w * 64 + lane] = o.u;
}

__global__ __launch_bounds__(256) void k_agg64(const unsigned char* __restrict__ t8,
                                               const int* __restrict__ rowptr,
                                               const int* __restrict__ col,
                                               const float* __restrict__ dinv,
                                               const float* __restrict__ bias,
                                               __bf16* __restrict__ out, int n) {
    int w = (int)((blockIdx.x * 256u + threadIdx.x) >> 6);
    int lane = threadIdx.x & 63;
    if (w >= n) return;
    float acc = fp8_to_f32((unsigned)t8[(size_t)w * 64 + lane]);
    int p = rowptr[w], pe = rowptr[w + 1];
    for (; p < pe; p += 16) {
        int4 c0 = *(const int4*)(col + p);
        int4 c1 = *(const int4*)(col + p + 4);
        int4 c2 = *(const int4*)(col + p + 8);
        int4 c3 = *(const int4*)(col + p + 12);
        unsigned u0 = t8[((size_t)c0.x << 6) + lane];
        unsigned u1 = t8[((size_t)c0.y << 6) + lane];
        unsigned u2 = t8[((size_t)c0.z << 6) + lane];
        unsigned u3 = t8[((size_t)c0.w << 6) + lane];
        unsigned u4 = t8[((size_t)c1.x << 6) + lane];
        unsigned u5 = t8[((size_t)c1.y << 6) + lane];
        unsigned u6 = t8[((size_t)c1.z << 6) + lane];
        unsigned u7 = t8[((size_t)c1.w << 6) + lane];
        unsigned u8 = t8[((size_t)c2.x << 6) + lane];
        unsigned u9 = t8[((size_t)c2.y << 6) + lane];
        unsigned ua = t8[((size_t)c2.z << 6) + lane];
        unsigned ub = t8[((size_t)c2.w << 6) + lane];
        unsigned uc = t8[((size_t)c3.x << 6) + lane];
        unsigned ud = t8[((size_t)c3.y << 6) + lane];
        unsigned ue = t8[((size_t)c3.z << 6) + lane];
        unsigned uf = t8[((size_t)c3.w << 6) + lane];
        acc += fp8_to_f32(u0);
        acc += fp8_to_f32(u1);
        acc += fp8_to_f32(u2);
        acc += fp8_to_f32(u3);
        acc += fp8_to_f32(u4);
        acc += fp8_to_f32(u5);
        acc += fp8_to_f32(u6);
        acc += fp8_to_f32(u7);
        acc += fp8_to_f32(u8);
        acc += fp8_to_f32(u9);
        acc += fp8_to_f32(ua);
        acc += fp8_to_f32(ub);
        acc += fp8_to_f32(uc);
        acc += fp8_to_f32(ud);
        acc += fp8_to_f32(ue);
        acc += fp8_to_f32(uf);
    }
    out[(size_t)w * 64 + lane] = (__bf16)fmaxf(dinv[w] * acc + bias[lane], 0.f);
}

// ---------------- fused mean-pool + MLP head ----------------
__global__ __launch_bounds__(256) void k_poolmlp(const unsigned short* __restrict__ h,
                                                 const int* __restrict__ gstart,
                                                 const float* __restrict__ demo,
                                                 const float* __restrict__ Wf1,
                                                 const float* __restrict__ bf1,
                                                 const float* __restrict__ Wf2,
                                                 const float* __restrict__ bf2,
                                                 const float* __restrict__ Wf3,
                                                 const float* __restrict__ bf3,
                                                 float* __restrict__ out, int G) {
    int g = blockIdx.x;
    int tid = threadIdx.x;
    int lane = tid & 63;
    int wv = tid >> 6;
    int s = gstart[g], e = gstart[g + 1];
    float acc = 0.f;
    for (int i = s + wv; i < e; i += 4)
        acc += __uint_as_float((unsigned)h[(size_t)i * 64 + lane] << 16);
    __shared__ float red[4][64];
    __shared__ float zin[72];
    __shared__ float z1[64];
    __shared__ float z2[32];
    red[wv][lane] = acc;
    if (tid >= 64 && tid < 72) zin[tid] = demo[g * 8 + (tid - 64)];
    __syncthreads();
    if (tid < 64) {
        float v = red[0][tid] + red[1][tid] + red[2][tid] + red[3][tid];
        zin[tid] = v / fmaxf((float)(e - s), 1.0f);
    }
    __syncthreads();
    if (tid < 64) {
        float a = bf1[tid];
        for (int k = 0; k < 72; k++) a += zin[k] * Wf1[k * 64 + tid];
        z1[tid] = fmaxf(a, 0.f);
    }
    __syncthreads();
    if (tid < 32) {
        float a2 = bf2[tid];
        for (int k = 0; k < 64; k++) a2 += z1[k] * Wf2[k * 32 + tid];
        z2[tid] = fmaxf(a2, 0.f);
    }
    __syncthreads();
    if (tid < 2) {
        float a3 = bf3[tid];
        for (int k = 0; k < 32; k++) a3 += z2[k] * Wf3[k * 2 + tid];
        out[g * 2 + tid] = a3;
    }
}

extern "C" void kernel_launch(void* const* d_in, const int* in_sizes, int n_in,
                              void* d_out, int out_size, void* d_ws, size_t ws_size,
                              hipStream_t stream) {
    const float* x    = (const float*)d_in[0];
    const int*   ei   = (const int*)d_in[1];
    const int*   batch= (const int*)d_in[2];
    const float* demo = (const float*)d_in[3];
    const float* W1   = (const float*)d_in[4];
    const float* b1   = (const float*)d_in[5];
    const float* W2   = (const float*)d_in[6];
    const float* b2   = (const float*)d_in[7];
    const float* W3   = (const float*)d_in[8];
    const float* b3   = (const float*)d_in[9];
    const float* Wf1  = (const float*)d_in[10];
    const float* bf1  = (const float*)d_in[11];
    const float* Wf2  = (const float*)d_in[12];
    const float* bf2  = (const float*)d_in[13];
    const float* Wf3  = (const float*)d_in[14];
    const float* bf3  = (const float*)d_in[15];
    float* out = (float*)d_out;

    const int n = in_sizes[0] / 128;  // 50000
    const int E = in_sizes[1] / 2;    // 600000
    const int G = in_sizes[3] / 8;    // 100
    const int Epad = E + 15 * n;      // worst-case padded CSR size (pad to 16)
    const int EC = (E + ECHUNK - 1) / ECHUNK;    // edge chunks (147)
    const int nbuck = (n + 127) / 128;           // row buckets (391)

    char* ws = (char*)d_ws;
    auto alloc = [&](size_t bytes) {
        char* p = ws;
        ws += (bytes + 255) & ~(size_t)255;
        return p;
    };
    float*  dinv   = (float*)alloc((size_t)n * 4);
    int*    rowptr = (int*)alloc((size_t)(n + 1) * 4);
    int*    gdeg   = (int*)alloc((size_t)n * 4);
    int*    btot   = (int*)alloc((size_t)nbuck * 4);
    int*    bbase  = (int*)alloc((size_t)(nbuck + 1) * 4);
    int*    col    = (int*)alloc((size_t)Epad * 4);
    int2*   binbuf = (int2*)alloc((size_t)EC * nbuck * BCAP * 8);
    int*    bcnt   = (int*)alloc((size_t)EC * nbuck * 4);
    unsigned char* tbf  = (unsigned char*)alloc((size_t)(n + 1) * 128);  // fp8 ts layers 1/2
    __bf16* hbuf   = (__bf16*)alloc((size_t)n * 128 * 2);                // agg out bf16
    unsigned char* t3bf = (unsigned char*)alloc((size_t)(n + 1) * 64);   // fp8 ts layer 3
    __bf16* h3     = (__bf16*)alloc((size_t)n * 64 * 2);                 // agg3 out (bf16)
    __bf16* Wp1h   = (__bf16*)alloc(128 * 128 * 2);
    __bf16* Wp1l   = (__bf16*)alloc(128 * 128 * 2);
    __bf16* Wp2h   = (__bf16*)alloc(128 * 128 * 2);
    __bf16* Wp2l   = (__bf16*)alloc(128 * 128 * 2);
    __bf16* Wp3h   = (__bf16*)alloc(128 * 64 * 2);
    __bf16* Wp3l   = (__bf16*)alloc(128 * 64 * 2);
    int*    gstart = (int*)alloc((size_t)(G + 1) * 4);

    const int* srcv = ei;
    const int* dstv = ei + E;

    int waves = (n + 15) / 16;
    int gemm_blocks = (waves + 3) / 4;
    int gemm1_blocks = (waves + 15) / 16;  // 16 waves per 1024-thread block
    int agg_blocks = (int)(((size_t)n * 64 + 255) / 256);

    // binning + gstart + wpack
    k_bin<<<EC + 1 + 5, 1024, 0, stream>>>(srcv, dstv, binbuf, bcnt, batch, gstart,
                                           W1, W2, W3, Wp1h, Wp1l, Wp2h, Wp2l,
                                           Wp3h, Wp3l, E, EC, nbuck, n, G);
    // per-bucket row degrees -> gdeg, dinv, btot (+ zero row n of ts buffers)
    k_rows<<<nbuck, 1024, 0, stream>>>(binbuf, bcnt, gdeg, dinv, btot,
                                       (unsigned int*)tbf, (unsigned int*)t3bf,
                                       n, EC, nbuck);
    // scan bucket totals
    k_base<<<1, 64, 0, stream>>>(btot, bbase, rowptr, n, nbuck);
    // finalize rowptr + staged coalesced col writeout || gemm1 (fp8 out)
    k_place<<<nbuck + gemm1_blocks, 1024, 0, stream>>>(binbuf, bcnt, gdeg, bbase,
                                                       rowptr, col, n, EC, nbuck,
                                                       x, Wp1h, Wp1l, dinv, tbf);

    // Layer 1 aggregation (fp8 gathers)
    k_agg128<<<agg_blocks, 256, 0, stream>>>((const unsigned short*)tbf, rowptr, col,
                                             dinv, b1, (unsigned int*)hbuf, n);
    // Layer 2
    k_gemm_bf16<8><<<gemm_blocks, 256, 0, stream>>>(hbuf, Wp2h, Wp2l, dinv, tbf, n);
    k_agg128<<<agg_blocks, 256, 0, stream>>>((const unsigned short*)tbf, rowptr, col,
                                             dinv, b2, (unsigned int*)hbuf, n);
    // Layer 3 (128 -> 64)
    k_gemm_bf16<4><<<gemm_blocks, 256, 0, stream>>>(hbuf, Wp3h, Wp3l, dinv, t3bf, n);
    k_agg64<<<agg_blocks, 256, 0, stream>>>((const unsigned char*)t3bf, rowptr, col,
                                            dinv, b3, h3, n);

    k_poolmlp<<<G, 256, 0, stream>>>((const unsigned short*)h3, gstart, demo,
                                     Wf1, bf1, Wf2, bf2, Wf3, bf3, out, G);
}